// Round 11
// baseline (260.261 us; speedup 1.0000x reference)
//
#include <hip/hip_runtime.h>
#include <hip/hip_bf16.h>

#define DM    2048
#define NH    16
#define DHD   128
#define TSEQ  2048
#define NBB   2
#define NTOK  (NBB*TSEQ)   // 4096

typedef __attribute__((ext_vector_type(8))) short bf16x8;
typedef __attribute__((ext_vector_type(4))) float f32x4;

typedef __attribute__((address_space(1))) const void GVoid;
typedef __attribute__((address_space(3))) void LVoid;
#define GLOAD16(SRC, DST) __builtin_amdgcn_global_load_lds((GVoid*)(SRC), (LVoid*)(DST), 16, 0, 0)

// branchless round-to-nearest-even bf16 (no NaN path; data has no NaNs).
__device__ __forceinline__ unsigned short f2bf(float f) {
  union { float f; unsigned u; } v; v.f = f;
  unsigned r = v.u + 0x7fffu + ((v.u >> 16) & 1u);
  return (unsigned short)(r >> 16);
}
__device__ __forceinline__ float bf2f(unsigned short h) {
  union { unsigned u; float f; } v; v.u = ((unsigned)h) << 16;
  return v.f;
}

#define QSCALE (0.08838834764831845f * 1.4426950408889634f)  // log2e/sqrt(128)

// ---------------- fp32 -> bf16 convert ----------------
__global__ void cvt_kernel(const float* __restrict__ in, unsigned short* __restrict__ out, int n4) {
  int i = blockIdx.x * blockDim.x + threadIdx.x;
  int stride = gridDim.x * blockDim.x;
  for (; i < n4; i += stride) {
    float4 v = reinterpret_cast<const float4*>(in)[i];
    ushort4 o;
    o.x = f2bf(v.x); o.y = f2bf(v.y); o.z = f2bf(v.z); o.w = f2bf(v.w);
    reinterpret_cast<ushort4*>(out)[i] = o;
  }
}

// 4 weight matrices (same size) -> one contiguous bf16 region
__global__ void cvt4_kernel(const float* __restrict__ a, const float* __restrict__ b,
                           const float* __restrict__ c, const float* __restrict__ d,
                           unsigned short* __restrict__ out, int n4per) {
  const float* in = (blockIdx.y == 0) ? a : (blockIdx.y == 1) ? b : (blockIdx.y == 2) ? c : d;
  unsigned short* o = out + (size_t)blockIdx.y * (size_t)n4per * 4;
  int i = blockIdx.x * blockDim.x + threadIdx.x;
  int stride = gridDim.x * blockDim.x;
  for (; i < n4per; i += stride) {
    float4 v = reinterpret_cast<const float4*>(in)[i];
    ushort4 ov;
    ov.x = f2bf(v.x); ov.y = f2bf(v.y); ov.z = f2bf(v.z); ov.w = f2bf(v.w);
    reinterpret_cast<ushort4*>(o)[i] = ov;
  }
}

// ---------------- RoPE cos/sin tables: [TSEQ][64] fp32 ----------------
__global__ void rope_table_kernel(const int* __restrict__ pos, float* __restrict__ ctab, float* __restrict__ stab) {
  int idx = blockIdx.x * blockDim.x + threadIdx.x;  // t*64 + i
  if (idx >= TSEQ * 64) return;
  int i = idx & 63;
  int t = idx >> 6;
  float freq = expf(-(2.0f * i / 128.0f) * 9.210340371976184f);  // theta^-(2i/128)
  float ang = (float)pos[t] * freq;
  ctab[idx] = cosf(ang);
  stab[idx] = sinf(ang);
}

// ---------------- V transpose: [NTOK][DM] -> [B*H][DHD][TSEQ] ----------------
__global__ void vtrans_kernel(const unsigned short* __restrict__ Vb, unsigned short* __restrict__ VTt) {
  __shared__ unsigned short tile[32][33];
  int t0 = blockIdx.x * 32, d0 = blockIdx.y * 32, bh = blockIdx.z;
  int h = bh & (NH - 1), b = bh >> 4;
  int tx = threadIdx.x, ty = threadIdx.y;
  #pragma unroll
  for (int i = 0; i < 4; i++) {
    int tt = t0 + ty + i * 8;
    tile[ty + i * 8][tx] = Vb[(size_t)(b * TSEQ + tt) * DM + h * DHD + d0 + tx];
  }
  __syncthreads();
  #pragma unroll
  for (int i = 0; i < 4; i++) {
    int d = d0 + ty + i * 8;
    VTt[((size_t)bh * DHD + d) * TSEQ + t0 + tx] = tile[tx][ty + i * 8];
  }
}

// ---------------- deep-pipelined GEMM, re-tiled for LDS-read economy ----------------
// BM=128 BN=256 BK=32, 8 waves (2M x 4N) -> wave tile 64x64 (MFMA:ds_read = 2.0).
// 3 LDS buffers x 24 KB = 72 KB -> 2 blocks/CU (cross-block barrier overlap).
// Depth-2 prefetch, counted vmcnt(3) (never 0 mid-loop). Rows are 64 B ->
// swizzle: 16B-chunk ^= (row>>1)&3 (uniform 2-way bank access = free, m136).
// MODE 0: C=A@Bt^T f32. MODE 1: fused QKV + RoPE epilogue (Q scaled+roped, K
// roped -> head-major; V token-major). Rotary partner = lane lr^1.
#define GBM 128
#define GBN 256
#define GBK 32
#define LDSB ((GBM + GBN) * GBK)   // shorts per buffer
template<int MODE>
__global__ __launch_bounds__(512, 4) void gemmk(
    const unsigned short* __restrict__ A,
    const unsigned short* __restrict__ Bt,
    void* __restrict__ Cp,
    unsigned short* __restrict__ QrO, unsigned short* __restrict__ KrO,
    const float* __restrict__ ct, const float* __restrict__ st,
    int K, int N, int NBN) {
  __shared__ unsigned short lds[3 * LDSB];  // 73728 B
  const int t = threadIdx.x;
  const int lane = t & 63, w = t >> 6;      // 8 waves
  const int wr = w >> 2, wc = w & 3;        // 2 (M) x 4 (N)
  const int lr = lane & 15, lg = lane >> 4;
  const int nwg = gridDim.x;
  const int swz = (blockIdx.x & 7) * (nwg >> 3) + (blockIdx.x >> 3);
  const int m0 = (swz / NBN) * GBM;
  const int n0g = (swz % NBN) * GBN;
  const int NT = K / GBK;

  f32x4 acc[4][4] = {};

  // stage K-tile kt into buffer b: A 128x32 (512 chunks, 1/thread),
  // B 256x32 (1024 chunks, 2/thread). LDS dest linear; source chunk
  // pre-swizzled by (row>>1)&3 (rule 21: same involution as the read).
  auto stage = [&](int kt, int b) {
    unsigned short* dst = &lds[b * LDSB];
    const size_t k0 = (size_t)kt * GBK;
    {
      int row = t >> 2, slot = t & 3;
      int ss = slot ^ ((row >> 1) & 3);
      GLOAD16(A + (size_t)(m0 + row) * K + k0 + ss * 8, dst + (size_t)(w * 64) * 8);
    }
    unsigned short* dstB = dst + GBM * GBK;
    #pragma unroll
    for (int c = 0; c < 2; c++) {
      int ci = c * 512 + t;
      int row = ci >> 2, slot = ci & 3;
      int ss = slot ^ ((row >> 1) & 3);
      GLOAD16(Bt + (size_t)(n0g + row) * K + k0 + ss * 8, dstB + (size_t)(c * 512 + w * 64) * 8);
    }
  };

  const unsigned short* buf = nullptr;
  auto ldA = [&](int mi) -> bf16x8 {
    int r = wr * 64 + mi * 16 + lr;
    int cb = (lg * 16) ^ (((r >> 1) & 3) << 4);
    return *(const bf16x8*)((const char*)buf + r * 64 + cb);
  };
  auto ldB = [&](int ni) -> bf16x8 {
    int r = wc * 64 + ni * 16 + lr;
    int cb = (lg * 16) ^ (((r >> 1) & 3) << 4);
    return *(const bf16x8*)((const char*)(buf + GBM * GBK) + r * 64 + cb);
  };

  stage(0, 0);
  stage(1, 1);

  for (int kt = 0; kt < NT; kt++) {
    // tile kt must be landed; tile kt+1's 3 loads stay in flight
    if (kt + 1 < NT) { asm volatile("s_waitcnt vmcnt(3)" ::: "memory"); }
    else             { asm volatile("s_waitcnt vmcnt(0)" ::: "memory"); }
    __builtin_amdgcn_s_barrier();
    buf = &lds[(kt % 3) * LDSB];

    bf16x8 bfr[4], afr[4];
    #pragma unroll
    for (int ni = 0; ni < 4; ni++) bfr[ni] = ldB(ni);
    #pragma unroll
    for (int mi = 0; mi < 4; mi++) afr[mi] = ldA(mi);
    if (kt + 2 < NT) stage(kt + 2, (kt + 2) % 3);  // buffer freed at this tile's top barrier
    asm volatile("s_waitcnt lgkmcnt(0)" ::: "memory");
    __builtin_amdgcn_sched_barrier(0);
    __builtin_amdgcn_s_setprio(1);
    #pragma unroll
    for (int mi = 0; mi < 4; mi++)
      #pragma unroll
      for (int ni = 0; ni < 4; ni++)
        acc[mi][ni] = __builtin_amdgcn_mfma_f32_16x16x32_bf16(afr[mi], bfr[ni], acc[mi][ni], 0, 0, 0);
    __builtin_amdgcn_s_setprio(0);
  }

  // epilogue: C/D layout col = lane&15, row = (lane>>4)*4 + j
  if (MODE == 0) {
    #pragma unroll
    for (int mi = 0; mi < 4; mi++)
      #pragma unroll
      for (int j = 0; j < 4; j++) {
        int row = m0 + wr * 64 + mi * 16 + lg * 4 + j;
        #pragma unroll
        for (int ni = 0; ni < 4; ni++) {
          int cg = n0g + wc * 64 + ni * 16 + lr;
          ((float*)Cp)[(size_t)row * N + cg] = acc[mi][ni][j];
        }
      }
  } else {
    const int sel = n0g >> 11;          // block-uniform (GBN=256 | 2048): 0=Q 1=K 2=V
    if (sel == 2) {
      #pragma unroll
      for (int mi = 0; mi < 4; mi++)
        #pragma unroll
        for (int j = 0; j < 4; j++) {
          int row = m0 + wr * 64 + mi * 16 + lg * 4 + j;
          #pragma unroll
          for (int ni = 0; ni < 4; ni++) {
            int c2 = (n0g + wc * 64 + ni * 16 + lr) & 2047;
            ((unsigned short*)Cp)[(size_t)row * DM + c2] = f2bf(acc[mi][ni][j]);
          }
        }
    } else {
      unsigned short* dst = sel ? KrO : QrO;
      const float qm = sel ? 1.0f : QSCALE;
      #pragma unroll
      for (int mi = 0; mi < 4; mi++)
        #pragma unroll
        for (int j = 0; j < 4; j++) {
          int row = m0 + wr * 64 + mi * 16 + lg * 4 + j;
          int bb = row >> 11, tt = row & (TSEQ - 1);
          #pragma unroll
          for (int ni = 0; ni < 4; ni++) {
            int c2 = (n0g + wc * 64 + ni * 16 + lr) & 2047;
            int d = c2 & 127, hh = c2 >> 7;
            float v = acc[mi][ni][j];
            float px = __shfl_xor(v, 1);   // rotary partner: col d^1 lives in lane lr^1
            float cc = ct[tt * 64 + (d >> 1)], ss = st[tt * 64 + (d >> 1)];
            float o = (d & 1) ? (px * ss + v * cc) : (v * cc - px * ss);
            dst[(((size_t)(bb * NH + hh)) * TSEQ + tt) * DHD + d] = f2bf(o * qm);
          }
        }
    }
  }
}

// ---------------- causal flash attention, 8-wave paired q-tiles (R10, passing) ----------------
__global__ __launch_bounds__(512, 4) void attn_kernel(
    const unsigned short* __restrict__ Qr,
    const unsigned short* __restrict__ Kr,
    const unsigned short* __restrict__ VTt,
    unsigned short* __restrict__ Oa) {
  __shared__ unsigned short Ks[64 * 128];
  __shared__ unsigned short Vs[128 * 64];
  __shared__ unsigned short Ps[8 * 16 * 64];
  const int t = threadIdx.x;
  const int lane = t & 63, w = t >> 6;     // 8 waves
  const int wv = w & 3, half = w >> 2;     // half 0 = tile B, 1 = tile A
  const int lr = lane & 15, lg = lane >> 4;
  const int p = blockIdx.x, bh = blockIdx.y;
  const int qA = p, qB = 31 - p;           // qB > qA always (p in 0..15)
  const int myq = half ? qA : qB;
  const int q0 = myq * 64;
  const int nt = myq + 1;                  // my tile count
  const int ntB = qB + 1;                  // staging trip count
  const unsigned short* Qh = Qr + (size_t)bh * TSEQ * DHD;
  const unsigned short* Kh = Kr + (size_t)bh * TSEQ * DHD;
  const unsigned short* Vh = VTt + (size_t)bh * DHD * TSEQ;

  bf16x8 qf[4];
  #pragma unroll
  for (int ks = 0; ks < 4; ks++)
    qf[ks] = *(const bf16x8*)&Qh[((size_t)(q0 + wv * 16 + lr)) * DHD + ks * 32 + lg * 8];

  f32x4 oacc[8] = {};
  float ps[4] = {};
  unsigned short* Pw = &Ps[w * 16 * 64];

  for (int jt = 0; jt < ntB; jt++) {
    const int j0 = jt * 64;
    // stage K: [64 kv][128 d] -> 16 chunks/row (row = ci>>4, slot = ci&15)
    #pragma unroll
    for (int c = 0; c < 2; c++) {
      int ci = c * 512 + t;
      int row = ci >> 4, slot = ci & 15;
      GLOAD16(Kh + (size_t)(j0 + row) * DHD + (slot ^ (row & 7)) * 8,
              &Ks[(c * 512 + w * 64) * 8]);
    }
    // stage V: [128 d][64 t] -> 8 chunks/row (row = ci>>3, slot = ci&7)
    #pragma unroll
    for (int c = 0; c < 2; c++) {
      int ci = c * 512 + t;
      int row = ci >> 3, slot = ci & 7;
      GLOAD16(Vh + (size_t)row * TSEQ + j0 + (slot ^ (row & 7)) * 8,
              &Vs[(c * 512 + w * 64) * 8]);
    }
    __syncthreads();
    if (jt < nt) {
      const bool diag = (jt == nt - 1);
      f32x4 sv[4] = {};
      #pragma unroll
      for (int n = 0; n < 4; n++) {
        #pragma unroll
        for (int ks = 0; ks < 4; ks++) {
          int row = n * 16 + lr;
          int byteoff = row * 256 + (((ks * 64 + lg * 16)) ^ ((row & 7) << 4));
          bf16x8 kf = *(const bf16x8*)((const char*)Ks + byteoff);
          sv[n] = __builtin_amdgcn_mfma_f32_16x16x32_bf16(qf[ks], kf, sv[n], 0, 0, 0);
        }
      }
      if (diag) {
        #pragma unroll
        for (int n = 0; n < 4; n++) {
          int kcol = j0 + n * 16 + lr;
          #pragma unroll
          for (int j = 0; j < 4; j++)
            if (kcol > q0 + wv * 16 + lg * 4 + j) sv[n][j] = -INFINITY;
        }
      }
      #pragma unroll
      for (int n = 0; n < 4; n++) {
        #pragma unroll
        for (int j = 0; j < 4; j++) {
          float pv = exp2f(sv[n][j]);
          ps[j] += pv;
          int prow = lg * 4 + j;
          int pcol = n * 16 + lr;
          int byteoff = (prow * 128 + pcol * 2) ^ ((prow & 7) << 4);
          *(unsigned short*)((char*)Pw + byteoff) = f2bf(pv);
        }
      }
      bf16x8 pa[2];
      #pragma unroll
      for (int kk = 0; kk < 2; kk++) {
        int byteoff = lr * 128 + (((kk * 64 + lg * 16)) ^ ((lr & 7) << 4));
        pa[kk] = *(const bf16x8*)((const char*)Pw + byteoff);
      }
      #pragma unroll
      for (int n2 = 0; n2 < 8; n2++) {
        #pragma unroll
        for (int kk = 0; kk < 2; kk++) {
          int row = n2 * 16 + lr;
          int byteoff = row * 128 + (((kk * 64 + lg * 16)) ^ ((row & 7) << 4));
          bf16x8 vf = *(const bf16x8*)((const char*)Vs + byteoff);
          oacc[n2] = __builtin_amdgcn_mfma_f32_16x16x32_bf16(pa[kk], vf, oacc[n2], 0, 0, 0);
        }
      }
    }
    __syncthreads();
  }

  #pragma unroll
  for (int m = 1; m < 16; m <<= 1)
    #pragma unroll
    for (int j = 0; j < 4; j++) ps[j] += __shfl_xor(ps[j], m);
  const int h = bh & (NH - 1), b = bh >> 4;
  #pragma unroll
  for (int j = 0; j < 4; j++) {
    float inv = 1.0f / ps[j];
    int tt = q0 + wv * 16 + lg * 4 + j;
    size_t base = ((size_t)(b * TSEQ + tt)) * DM + h * DHD;
    #pragma unroll
    for (int n2 = 0; n2 < 8; n2++)
      Oa[base + n2 * 16 + lr] = f2bf(oacc[n2][j] * inv);
  }
}

// ---------------- launch ----------------
extern "C" void kernel_launch(void* const* d_in, const int* in_sizes, int n_in,
                              void* d_out, int out_size, void* d_ws, size_t ws_size,
                              hipStream_t stream) {
  const float* x  = (const float*)d_in[0];
  const int*   pos = (const int*)d_in[1];
  const float* Wq = (const float*)d_in[2];
  const float* Wk = (const float*)d_in[3];
  const float* Wv = (const float*)d_in[4];
  const float* Wp = (const float*)d_in[5];
  float* out = (float*)d_out;

  char* wsp = (char*)d_ws;
  auto alloc = [&](size_t bytes) { char* p = wsp; wsp += (bytes + 255) & ~(size_t)255; return p; };
  unsigned short* xb  = (unsigned short*)alloc((size_t)NTOK * DM * 2);  // x; later Oa
  unsigned short* wqb = (unsigned short*)alloc((size_t)DM * DM * 2);    // wq/wk/wv/wp contiguous
  unsigned short* wkb = (unsigned short*)alloc((size_t)DM * DM * 2);
  unsigned short* wvb = (unsigned short*)alloc((size_t)DM * DM * 2);
  unsigned short* wpb = (unsigned short*)alloc((size_t)DM * DM * 2);
  unsigned short* Qb  = (unsigned short*)alloc((size_t)NTOK * DM * 2);  // roped Q, head-major
  unsigned short* Kb  = (unsigned short*)alloc((size_t)NTOK * DM * 2);  // roped K, head-major
  unsigned short* Vb  = (unsigned short*)alloc((size_t)NTOK * DM * 2);  // V token-major
  unsigned short* VTt = (unsigned short*)alloc((size_t)NTOK * DM * 2);  // V^T head-major
  float* ctab = (float*)alloc((size_t)TSEQ * 64 * 4);
  float* stab = (float*)alloc((size_t)TSEQ * 64 * 4);
  unsigned short* Oa = xb;   // x dead after QKV projection
  (void)wkb; (void)wvb;

  int n4x = NTOK * DM / 4, n4w = DM * DM / 4;
  cvt_kernel<<<2048, 256, 0, stream>>>(x, xb, n4x);
  cvt4_kernel<<<dim3(256, 4), 256, 0, stream>>>(Wq, Wk, Wv, Wp, wqb, n4w);
  rope_table_kernel<<<(TSEQ * 64) / 256, 256, 0, stream>>>(pos, ctab, stab);

  // fused QKV projection + RoPE epilogue: grid 32x24 = 768 (%8 == 0)
  gemmk<1><<<(NTOK / GBM) * (3 * DM / GBN), 512, 0, stream>>>(
      xb, wqb, Vb, Qb, Kb, ctab, stab, DM, DM, 3 * DM / GBN);

  vtrans_kernel<<<dim3(TSEQ / 32, DHD / 32, NBB * NH), dim3(32, 8), 0, stream>>>(Vb, VTt);

  attn_kernel<<<dim3(16, NBB * NH), 512, 0, stream>>>(Qb, Kb, VTt, Oa);

  // output projection: grid 32x8 = 256
  gemmk<0><<<(NTOK / GBM) * (DM / GBN), 512, 0, stream>>>(
      Oa, wpb, out, nullptr, nullptr, nullptr, nullptr, DM, DM, DM / GBN);
}

// Round 12
// 255.991 us; speedup vs baseline: 1.0167x; 1.0167x over previous
//
#include <hip/hip_runtime.h>
#include <hip/hip_bf16.h>

#define DM    2048
#define NH    16
#define DHD   128
#define TSEQ  2048
#define NBB   2
#define NTOK  (NBB*TSEQ)   // 4096

typedef __attribute__((ext_vector_type(8))) short bf16x8;
typedef __attribute__((ext_vector_type(4))) float f32x4;

typedef __attribute__((address_space(1))) const void GVoid;
typedef __attribute__((address_space(3))) void LVoid;
#define GLOAD16(SRC, DST) __builtin_amdgcn_global_load_lds((GVoid*)(SRC), (LVoid*)(DST), 16, 0, 0)

// branchless round-to-nearest-even bf16 (no NaN path; data has no NaNs).
__device__ __forceinline__ unsigned short f2bf(float f) {
  union { float f; unsigned u; } v; v.f = f;
  unsigned r = v.u + 0x7fffu + ((v.u >> 16) & 1u);
  return (unsigned short)(r >> 16);
}
__device__ __forceinline__ float bf2f(unsigned short h) {
  union { unsigned u; float f; } v; v.u = ((unsigned)h) << 16;
  return v.f;
}

#define QSCALE (0.08838834764831845f * 1.4426950408889634f)  // log2e/sqrt(128)

// ---------------- fp32 -> bf16 convert ----------------
__global__ void cvt_kernel(const float* __restrict__ in, unsigned short* __restrict__ out, int n4) {
  int i = blockIdx.x * blockDim.x + threadIdx.x;
  int stride = gridDim.x * blockDim.x;
  for (; i < n4; i += stride) {
    float4 v = reinterpret_cast<const float4*>(in)[i];
    ushort4 o;
    o.x = f2bf(v.x); o.y = f2bf(v.y); o.z = f2bf(v.z); o.w = f2bf(v.w);
    reinterpret_cast<ushort4*>(out)[i] = o;
  }
}

// 4 weight matrices (same size) -> one contiguous bf16 region
__global__ void cvt4_kernel(const float* __restrict__ a, const float* __restrict__ b,
                           const float* __restrict__ c, const float* __restrict__ d,
                           unsigned short* __restrict__ out, int n4per) {
  const float* in = (blockIdx.y == 0) ? a : (blockIdx.y == 1) ? b : (blockIdx.y == 2) ? c : d;
  unsigned short* o = out + (size_t)blockIdx.y * (size_t)n4per * 4;
  int i = blockIdx.x * blockDim.x + threadIdx.x;
  int stride = gridDim.x * blockDim.x;
  for (; i < n4per; i += stride) {
    float4 v = reinterpret_cast<const float4*>(in)[i];
    ushort4 ov;
    ov.x = f2bf(v.x); ov.y = f2bf(v.y); ov.z = f2bf(v.z); ov.w = f2bf(v.w);
    reinterpret_cast<ushort4*>(o)[i] = ov;
  }
}

// ---------------- RoPE cos/sin tables: [TSEQ][64] fp32 ----------------
__global__ void rope_table_kernel(const int* __restrict__ pos, float* __restrict__ ctab, float* __restrict__ stab) {
  int idx = blockIdx.x * blockDim.x + threadIdx.x;  // t*64 + i
  if (idx >= TSEQ * 64) return;
  int i = idx & 63;
  int t = idx >> 6;
  float freq = expf(-(2.0f * i / 128.0f) * 9.210340371976184f);  // theta^-(2i/128)
  float ang = (float)pos[t] * freq;
  ctab[idx] = cosf(ang);
  stab[idx] = sinf(ang);
}

// ---------------- V transpose: [NTOK][DM] -> [B*H][DHD][TSEQ] ----------------
__global__ void vtrans_kernel(const unsigned short* __restrict__ Vb, unsigned short* __restrict__ VTt) {
  __shared__ unsigned short tile[32][33];
  int t0 = blockIdx.x * 32, d0 = blockIdx.y * 32, bh = blockIdx.z;
  int h = bh & (NH - 1), b = bh >> 4;
  int tx = threadIdx.x, ty = threadIdx.y;
  #pragma unroll
  for (int i = 0; i < 4; i++) {
    int tt = t0 + ty + i * 8;
    tile[ty + i * 8][tx] = Vb[(size_t)(b * TSEQ + tt) * DM + h * DHD + d0 + tx];
  }
  __syncthreads();
  #pragma unroll
  for (int i = 0; i < 4; i++) {
    int d = d0 + ty + i * 8;
    VTt[((size_t)bh * DHD + d) * TSEQ + t0 + tx] = tile[tx][ty + i * 8];
  }
}

// ---------------- gemmk: BM=128 BN=256 BK=32 (QKV + RoPE epilogue) ----------------
#define GBM 128
#define GBN 256
#define GBK 32
#define LDSB ((GBM + GBN) * GBK)
template<int MODE>
__global__ __launch_bounds__(512, 4) void gemmk(
    const unsigned short* __restrict__ A,
    const unsigned short* __restrict__ Bt,
    void* __restrict__ Cp,
    unsigned short* __restrict__ QrO, unsigned short* __restrict__ KrO,
    const float* __restrict__ ct, const float* __restrict__ st,
    int K, int N, int NBN) {
  __shared__ unsigned short lds[3 * LDSB];  // 73728 B
  const int t = threadIdx.x;
  const int lane = t & 63, w = t >> 6;      // 8 waves
  const int wr = w >> 2, wc = w & 3;        // 2 (M) x 4 (N)
  const int lr = lane & 15, lg = lane >> 4;
  const int nwg = gridDim.x;
  const int swz = (blockIdx.x & 7) * (nwg >> 3) + (blockIdx.x >> 3);
  const int m0 = (swz / NBN) * GBM;
  const int n0g = (swz % NBN) * GBN;
  const int NT = K / GBK;

  f32x4 acc[4][4] = {};

  auto stage = [&](int kt, int b) {
    unsigned short* dst = &lds[b * LDSB];
    const size_t k0 = (size_t)kt * GBK;
    {
      int row = t >> 2, slot = t & 3;
      int ss = slot ^ ((row >> 1) & 3);
      GLOAD16(A + (size_t)(m0 + row) * K + k0 + ss * 8, dst + (size_t)(w * 64) * 8);
    }
    unsigned short* dstB = dst + GBM * GBK;
    #pragma unroll
    for (int c = 0; c < 2; c++) {
      int ci = c * 512 + t;
      int row = ci >> 2, slot = ci & 3;
      int ss = slot ^ ((row >> 1) & 3);
      GLOAD16(Bt + (size_t)(n0g + row) * K + k0 + ss * 8, dstB + (size_t)(c * 512 + w * 64) * 8);
    }
  };

  const unsigned short* buf = nullptr;
  auto ldA = [&](int mi) -> bf16x8 {
    int r = wr * 64 + mi * 16 + lr;
    int cb = (lg * 16) ^ (((r >> 1) & 3) << 4);
    return *(const bf16x8*)((const char*)buf + r * 64 + cb);
  };
  auto ldB = [&](int ni) -> bf16x8 {
    int r = wc * 64 + ni * 16 + lr;
    int cb = (lg * 16) ^ (((r >> 1) & 3) << 4);
    return *(const bf16x8*)((const char*)(buf + GBM * GBK) + r * 64 + cb);
  };

  stage(0, 0);
  stage(1, 1);

  for (int kt = 0; kt < NT; kt++) {
    if (kt + 1 < NT) { asm volatile("s_waitcnt vmcnt(3)" ::: "memory"); }
    else             { asm volatile("s_waitcnt vmcnt(0)" ::: "memory"); }
    __builtin_amdgcn_s_barrier();
    buf = &lds[(kt % 3) * LDSB];

    bf16x8 bfr[4], afr[4];
    #pragma unroll
    for (int ni = 0; ni < 4; ni++) bfr[ni] = ldB(ni);
    #pragma unroll
    for (int mi = 0; mi < 4; mi++) afr[mi] = ldA(mi);
    if (kt + 2 < NT) stage(kt + 2, (kt + 2) % 3);
    asm volatile("s_waitcnt lgkmcnt(0)" ::: "memory");
    __builtin_amdgcn_sched_barrier(0);
    __builtin_amdgcn_s_setprio(1);
    #pragma unroll
    for (int mi = 0; mi < 4; mi++)
      #pragma unroll
      for (int ni = 0; ni < 4; ni++)
        acc[mi][ni] = __builtin_amdgcn_mfma_f32_16x16x32_bf16(afr[mi], bfr[ni], acc[mi][ni], 0, 0, 0);
    __builtin_amdgcn_s_setprio(0);
  }

  if (MODE == 0) {
    #pragma unroll
    for (int mi = 0; mi < 4; mi++)
      #pragma unroll
      for (int j = 0; j < 4; j++) {
        int row = m0 + wr * 64 + mi * 16 + lg * 4 + j;
        #pragma unroll
        for (int ni = 0; ni < 4; ni++) {
          int cg = n0g + wc * 64 + ni * 16 + lr;
          ((float*)Cp)[(size_t)row * N + cg] = acc[mi][ni][j];
        }
      }
  } else {
    const int sel = n0g >> 11;          // block-uniform: 0=Q 1=K 2=V
    if (sel == 2) {
      #pragma unroll
      for (int mi = 0; mi < 4; mi++)
        #pragma unroll
        for (int j = 0; j < 4; j++) {
          int row = m0 + wr * 64 + mi * 16 + lg * 4 + j;
          #pragma unroll
          for (int ni = 0; ni < 4; ni++) {
            int c2 = (n0g + wc * 64 + ni * 16 + lr) & 2047;
            ((unsigned short*)Cp)[(size_t)row * DM + c2] = f2bf(acc[mi][ni][j]);
          }
        }
    } else {
      unsigned short* dst = sel ? KrO : QrO;
      const float qm = sel ? 1.0f : QSCALE;
      #pragma unroll
      for (int mi = 0; mi < 4; mi++)
        #pragma unroll
        for (int j = 0; j < 4; j++) {
          int row = m0 + wr * 64 + mi * 16 + lg * 4 + j;
          int bb = row >> 11, tt = row & (TSEQ - 1);
          #pragma unroll
          for (int ni = 0; ni < 4; ni++) {
            int c2 = (n0g + wc * 64 + ni * 16 + lr) & 2047;
            int d = c2 & 127, hh = c2 >> 7;
            float v = acc[mi][ni][j];
            float px = __shfl_xor(v, 1);
            float cc = ct[tt * 64 + (d >> 1)], ss = st[tt * 64 + (d >> 1)];
            float o = (d & 1) ? (px * ss + v * cc) : (v * cc - px * ss);
            dst[(((size_t)(bb * NH + hh)) * TSEQ + tt) * DHD + d] = f2bf(o * qm);
          }
        }
    }
  }
}

// ---------------- gemm256: BM=256 BN=128 BK=64, 1 block/CU (proj) ----------------
// R10-proven. Grid 256 = all CUs busy (R11 lesson: gemmk's 2/CU + 256-block
// grid left half the chip idle on proj).
#define G2M 256
#define G2N 128
#define G2K 64
__global__ __launch_bounds__(512, 2) void gemm256(
    const unsigned short* __restrict__ A,
    const unsigned short* __restrict__ Bt,
    float* __restrict__ Cp, int K, int N, int NBN) {
  __shared__ unsigned short lds[3 * (G2M + G2N) * G2K];  // 147456 B
  const int t = threadIdx.x;
  const int lane = t & 63, w = t >> 6;
  const int wr = w >> 2, wc = w & 3;
  const int lr = lane & 15, lg = lane >> 4;
  const int nwg = gridDim.x;
  const int swz = (blockIdx.x & 7) * (nwg >> 3) + (blockIdx.x >> 3);
  const int m0 = (swz / NBN) * G2M;
  const int n0g = (swz % NBN) * G2N;
  const int NT = K / G2K;

  f32x4 acc[8][2] = {};

  auto stageA = [&](int kt, int b) {
    unsigned short* dst = &lds[b * (G2M + G2N) * G2K];
    const size_t k0 = (size_t)kt * G2K;
    #pragma unroll
    for (int c = 0; c < 4; c++) {
      int i = c * 512 + t;
      int row = i >> 3, slot = i & 7;
      int sslot = slot ^ (row & 7);
      GLOAD16(A + (size_t)(m0 + row) * K + k0 + sslot * 8,
              dst + (size_t)(c * 512 + w * 64) * 8);
    }
  };
  auto stageB = [&](int kt, int b) {
    unsigned short* dst = &lds[b * (G2M + G2N) * G2K + G2M * G2K];
    const size_t k0 = (size_t)kt * G2K;
    #pragma unroll
    for (int c = 0; c < 2; c++) {
      int i = c * 512 + t;
      int row = i >> 3, slot = i & 7;
      int sslot = slot ^ (row & 7);
      GLOAD16(Bt + (size_t)(n0g + row) * K + k0 + sslot * 8,
              dst + (size_t)(c * 512 + w * 64) * 8);
    }
  };

  const unsigned short* bufA = nullptr;
  const unsigned short* bufB = nullptr;
  auto ldA = [&](int mi, int ks) -> bf16x8 {
    int r = wr * 128 + mi * 16 + lr;
    int cb = (ks * 64 + lg * 16) ^ ((r & 7) << 4);
    return *(const bf16x8*)((const char*)bufA + r * 128 + cb);
  };
  auto ldB = [&](int ni, int ks) -> bf16x8 {
    int r = wc * 32 + ni * 16 + lr;
    int cb = (ks * 64 + lg * 16) ^ ((r & 7) << 4);
    return *(const bf16x8*)((const char*)bufB + r * 128 + cb);
  };

  stageA(0, 0); stageB(0, 0);
  stageA(1, 1); stageB(1, 1);

  for (int kt = 0; kt < NT; kt++) {
    if (kt + 1 < NT) { asm volatile("s_waitcnt vmcnt(6)" ::: "memory"); }
    else             { asm volatile("s_waitcnt vmcnt(0)" ::: "memory"); }
    __builtin_amdgcn_s_barrier();
    const int b = kt % 3;
    bufA = &lds[b * (G2M + G2N) * G2K];
    bufB = bufA + G2M * G2K;
    const int kt2 = kt + 2, b2 = kt2 % 3;

    bf16x8 bfr[2][2], afr[4][2];
    #pragma unroll
    for (int ni = 0; ni < 2; ni++)
      #pragma unroll
      for (int ks = 0; ks < 2; ks++) bfr[ni][ks] = ldB(ni, ks);
    #pragma unroll
    for (int mi = 0; mi < 4; mi++)
      #pragma unroll
      for (int ks = 0; ks < 2; ks++) afr[mi][ks] = ldA(mi, ks);
    if (kt2 < NT) stageA(kt2, b2);
    asm volatile("s_waitcnt lgkmcnt(0)" ::: "memory");
    __builtin_amdgcn_sched_barrier(0);
    __builtin_amdgcn_s_setprio(1);
    #pragma unroll
    for (int mi = 0; mi < 4; mi++)
      #pragma unroll
      for (int ni = 0; ni < 2; ni++)
        #pragma unroll
        for (int ks = 0; ks < 2; ks++)
          acc[mi][ni] = __builtin_amdgcn_mfma_f32_16x16x32_bf16(afr[mi][ks], bfr[ni][ks], acc[mi][ni], 0, 0, 0);
    __builtin_amdgcn_s_setprio(0);
    __builtin_amdgcn_s_barrier();

    bf16x8 afr2[4][2];
    #pragma unroll
    for (int mi = 0; mi < 4; mi++)
      #pragma unroll
      for (int ks = 0; ks < 2; ks++) afr2[mi][ks] = ldA(mi + 4, ks);
    if (kt2 < NT) stageB(kt2, b2);
    asm volatile("s_waitcnt lgkmcnt(0)" ::: "memory");
    __builtin_amdgcn_sched_barrier(0);
    __builtin_amdgcn_s_setprio(1);
    #pragma unroll
    for (int mi = 0; mi < 4; mi++)
      #pragma unroll
      for (int ni = 0; ni < 2; ni++)
        #pragma unroll
        for (int ks = 0; ks < 2; ks++)
          acc[mi + 4][ni] = __builtin_amdgcn_mfma_f32_16x16x32_bf16(afr2[mi][ks], bfr[ni][ks], acc[mi + 4][ni], 0, 0, 0);
    __builtin_amdgcn_s_setprio(0);
  }

  #pragma unroll
  for (int mi = 0; mi < 8; mi++)
    #pragma unroll
    for (int j = 0; j < 4; j++) {
      int row = m0 + wr * 128 + mi * 16 + lg * 4 + j;
      #pragma unroll
      for (int ni = 0; ni < 2; ni++) {
        int cg = n0g + wc * 32 + ni * 16 + lr;
        Cp[(size_t)row * N + cg] = acc[mi][ni][j];
      }
    }
}

// ---------------- causal flash attention v3: kv-split halves, LPT grid ----------------
// One 64-row q-tile per block (1024 blocks, descending-q dispatch for LPT).
// No-max softmax makes O and l pure sums -> wave-half 0 accumulates kv-tiles
// [0,n0), half 1 [n0,ntot); epilogue merges by addition via LDS. Trips =
// ceil(ntot/2) = 1..16 (vs 17..32 makespan-32 in the paired version).
__global__ __launch_bounds__(512, 4) void attn_kernel(
    const unsigned short* __restrict__ Qr,
    const unsigned short* __restrict__ Kr,
    const unsigned short* __restrict__ VTt,
    unsigned short* __restrict__ Oa) {
  __shared__ unsigned short Ks[2][64 * 128];   // [half]
  __shared__ unsigned short Vs[2][128 * 64];
  __shared__ unsigned short Ps[8 * 16 * 64];
  const int t = threadIdx.x;
  const int lane = t & 63, w = t >> 6;     // 8 waves
  const int wv = w & 3, half = w >> 2;     // wv: 16-row slice; half: kv range
  const int th = t & 255;                  // thread within half (256)
  const int lr = lane & 15, lg = lane >> 4;
  const int bid = blockIdx.x;
  const int qi = 31 - (bid >> 5);          // descending q: longest blocks first
  const int bh = bid & 31;
  const int q0 = qi * 64;
  const int ntot = qi + 1;
  const int n0 = (ntot + 1) >> 1;          // half0: [0,n0)  half1: [n0,ntot)
  const unsigned short* Qh = Qr + (size_t)bh * TSEQ * DHD;
  const unsigned short* Kh = Kr + (size_t)bh * TSEQ * DHD;
  const unsigned short* Vh = VTt + (size_t)bh * DHD * TSEQ;

  bf16x8 qf[4];
  #pragma unroll
  for (int ks = 0; ks < 4; ks++)
    qf[ks] = *(const bf16x8*)&Qh[((size_t)(q0 + wv * 16 + lr)) * DHD + ks * 32 + lg * 8];

  f32x4 oacc[8] = {};
  float ps[4] = {};
  unsigned short* Pw = &Ps[w * 16 * 64];

  for (int jt = 0; jt < n0; jt++) {
    const int j = half ? (n0 + jt) : jt;
    const bool act = j < ntot;             // half1 may have one fewer tile
    if (act) {
      const int j0 = j * 64;
      // stage my half's K tile: [64 kv][128 d], 1024 chunks / 256 thr = 4 each
      #pragma unroll
      for (int c = 0; c < 4; c++) {
        int ci = c * 256 + th;
        int row = ci >> 4, slot = ci & 15;
        GLOAD16(Kh + (size_t)(j0 + row) * DHD + (slot ^ (row & 7)) * 8,
                &Ks[half][(c * 4 + wv) * 512]);
      }
      // stage my half's V tile: [128 d][64 t], 8 chunks/row
      #pragma unroll
      for (int c = 0; c < 4; c++) {
        int ci = c * 256 + th;
        int row = ci >> 3, slot = ci & 7;
        GLOAD16(Vh + (size_t)row * TSEQ + j0 + (slot ^ (row & 7)) * 8,
                &Vs[half][(c * 4 + wv) * 512]);
      }
    }
    __syncthreads();
    if (act) {
      const int j0 = j * 64;
      const bool diag = (j == qi);
      f32x4 sv[4] = {};
      #pragma unroll
      for (int n = 0; n < 4; n++) {
        #pragma unroll
        for (int ks = 0; ks < 4; ks++) {
          int row = n * 16 + lr;
          int byteoff = row * 256 + (((ks * 64 + lg * 16)) ^ ((row & 7) << 4));
          bf16x8 kf = *(const bf16x8*)((const char*)&Ks[half][0] + byteoff);
          sv[n] = __builtin_amdgcn_mfma_f32_16x16x32_bf16(qf[ks], kf, sv[n], 0, 0, 0);
        }
      }
      if (diag) {
        #pragma unroll
        for (int n = 0; n < 4; n++) {
          int kcol = j0 + n * 16 + lr;
          #pragma unroll
          for (int j2 = 0; j2 < 4; j2++)
            if (kcol > q0 + wv * 16 + lg * 4 + j2) sv[n][j2] = -INFINITY;
        }
      }
      #pragma unroll
      for (int n = 0; n < 4; n++) {
        #pragma unroll
        for (int j2 = 0; j2 < 4; j2++) {
          float pv = exp2f(sv[n][j2]);
          ps[j2] += pv;
          int prow = lg * 4 + j2;
          int pcol = n * 16 + lr;
          int byteoff = (prow * 128 + pcol * 2) ^ ((prow & 7) << 4);
          *(unsigned short*)((char*)Pw + byteoff) = f2bf(pv);
        }
      }
      bf16x8 pa[2];
      #pragma unroll
      for (int kk = 0; kk < 2; kk++) {
        int byteoff = lr * 128 + (((kk * 64 + lg * 16)) ^ ((lr & 7) << 4));
        pa[kk] = *(const bf16x8*)((const char*)Pw + byteoff);
      }
      #pragma unroll
      for (int n2 = 0; n2 < 8; n2++) {
        #pragma unroll
        for (int kk = 0; kk < 2; kk++) {
          int row = n2 * 16 + lr;
          int byteoff = row * 128 + (((kk * 64 + lg * 16)) ^ ((row & 7) << 4));
          bf16x8 vf = *(const bf16x8*)((const char*)&Vs[half][0] + byteoff);
          oacc[n2] = __builtin_amdgcn_mfma_f32_16x16x32_bf16(pa[kk], vf, oacc[n2], 0, 0, 0);
        }
      }
    }
    __syncthreads();
  }

  // merge: half1 -> LDS, half0 adds (O and l are pure sums: no-max softmax)
  float* M  = (float*)&Ks[0][0];   // 64 rows x 128 cols f32 = 32 KB (Ks area)
  float* P2 = (float*)&Vs[0][0];   // 64 rows x 16 lanes f32 = 4 KB
  if (half == 1) {
    #pragma unroll
    for (int n2 = 0; n2 < 8; n2++)
      #pragma unroll
      for (int j = 0; j < 4; j++)
        M[((wv * 16 + lg * 4 + j) * 8 + n2) * 16 + lr] = oacc[n2][j];
    #pragma unroll
    for (int j = 0; j < 4; j++)
      P2[(wv * 16 + lg * 4 + j) * 16 + lr] = ps[j];
  }
  __syncthreads();
  if (half == 0) {
    #pragma unroll
    for (int n2 = 0; n2 < 8; n2++)
      #pragma unroll
      for (int j = 0; j < 4; j++)
        oacc[n2][j] += M[((wv * 16 + lg * 4 + j) * 8 + n2) * 16 + lr];
    #pragma unroll
    for (int j = 0; j < 4; j++) ps[j] += P2[(wv * 16 + lg * 4 + j) * 16 + lr];
    #pragma unroll
    for (int m = 1; m < 16; m <<= 1)
      #pragma unroll
      for (int j = 0; j < 4; j++) ps[j] += __shfl_xor(ps[j], m);
    const int h = bh & (NH - 1), b = bh >> 4;
    #pragma unroll
    for (int j = 0; j < 4; j++) {
      float inv = 1.0f / ps[j];
      int tt = q0 + wv * 16 + lg * 4 + j;
      size_t base = ((size_t)(b * TSEQ + tt)) * DM + h * DHD;
      #pragma unroll
      for (int n2 = 0; n2 < 8; n2++)
        Oa[base + n2 * 16 + lr] = f2bf(oacc[n2][j] * inv);
    }
  }
}

// ---------------- launch ----------------
extern "C" void kernel_launch(void* const* d_in, const int* in_sizes, int n_in,
                              void* d_out, int out_size, void* d_ws, size_t ws_size,
                              hipStream_t stream) {
  const float* x  = (const float*)d_in[0];
  const int*   pos = (const int*)d_in[1];
  const float* Wq = (const float*)d_in[2];
  const float* Wk = (const float*)d_in[3];
  const float* Wv = (const float*)d_in[4];
  const float* Wp = (const float*)d_in[5];
  float* out = (float*)d_out;

  char* wsp = (char*)d_ws;
  auto alloc = [&](size_t bytes) { char* p = wsp; wsp += (bytes + 255) & ~(size_t)255; return p; };
  unsigned short* xb  = (unsigned short*)alloc((size_t)NTOK * DM * 2);  // x; later Oa
  unsigned short* wqb = (unsigned short*)alloc((size_t)DM * DM * 2);    // wq/wk/wv/wp contiguous
  unsigned short* wkb = (unsigned short*)alloc((size_t)DM * DM * 2);
  unsigned short* wvb = (unsigned short*)alloc((size_t)DM * DM * 2);
  unsigned short* wpb = (unsigned short*)alloc((size_t)DM * DM * 2);
  unsigned short* Qb  = (unsigned short*)alloc((size_t)NTOK * DM * 2);  // roped Q, head-major
  unsigned short* Kb  = (unsigned short*)alloc((size_t)NTOK * DM * 2);  // roped K, head-major
  unsigned short* Vb  = (unsigned short*)alloc((size_t)NTOK * DM * 2);  // V token-major
  unsigned short* VTt = (unsigned short*)alloc((size_t)NTOK * DM * 2);  // V^T head-major
  float* ctab = (float*)alloc((size_t)TSEQ * 64 * 4);
  float* stab = (float*)alloc((size_t)TSEQ * 64 * 4);
  unsigned short* Oa = xb;   // x dead after QKV projection
  (void)wkb; (void)wvb;

  int n4x = NTOK * DM / 4, n4w = DM * DM / 4;
  cvt_kernel<<<2048, 256, 0, stream>>>(x, xb, n4x);
  cvt4_kernel<<<dim3(256, 4), 256, 0, stream>>>(Wq, Wk, Wv, Wp, wqb, n4w);
  rope_table_kernel<<<(TSEQ * 64) / 256, 256, 0, stream>>>(pos, ctab, stab);

  // fused QKV projection + RoPE epilogue: grid 32x24 = 768
  gemmk<1><<<(NTOK / GBM) * (3 * DM / GBN), 512, 0, stream>>>(
      xb, wqb, Vb, Qb, Kb, ctab, stab, DM, DM, 3 * DM / GBN);

  vtrans_kernel<<<dim3(TSEQ / 32, DHD / 32, NBB * NH), dim3(32, 8), 0, stream>>>(Vb, VTt);

  // attention: 32 q-tiles x 32 heads = 1024 blocks, descending-q (LPT)
  attn_kernel<<<1024, 512, 0, stream>>>(Qb, Kb, VTt, Oa);

  // output projection: 256-block gemm256, 1 block/CU = all CUs busy
  gemm256<<<(NTOK / G2M) * (DM / G2N), 512, 0, stream>>>(Oa, wpb, out, DM, DM, DM / G2N);
}

// Round 13
// 241.019 us; speedup vs baseline: 1.0798x; 1.0621x over previous
//
#include <hip/hip_runtime.h>
#include <hip/hip_bf16.h>

#define DM    2048
#define NH    16
#define DHD   128
#define TSEQ  2048
#define NBB   2
#define NTOK  (NBB*TSEQ)   // 4096

typedef __attribute__((ext_vector_type(8))) short bf16x8;
typedef __attribute__((ext_vector_type(4))) float f32x4;

typedef __attribute__((address_space(1))) const void GVoid;
typedef __attribute__((address_space(3))) void LVoid;
#define GLOAD16(SRC, DST) __builtin_amdgcn_global_load_lds((GVoid*)(SRC), (LVoid*)(DST), 16, 0, 0)

// branchless round-to-nearest-even bf16 (no NaN path; data has no NaNs).
__device__ __forceinline__ unsigned short f2bf(float f) {
  union { float f; unsigned u; } v; v.f = f;
  unsigned r = v.u + 0x7fffu + ((v.u >> 16) & 1u);
  return (unsigned short)(r >> 16);
}
__device__ __forceinline__ float bf2f(unsigned short h) {
  union { unsigned u; float f; } v; v.u = ((unsigned)h) << 16;
  return v.f;
}

#define QSCALE (0.08838834764831845f * 1.4426950408889634f)  // log2e/sqrt(128)

// ---------------- fp32 -> bf16 convert ----------------
__global__ void cvt_kernel(const float* __restrict__ in, unsigned short* __restrict__ out, int n4) {
  int i = blockIdx.x * blockDim.x + threadIdx.x;
  int stride = gridDim.x * blockDim.x;
  for (; i < n4; i += stride) {
    float4 v = reinterpret_cast<const float4*>(in)[i];
    ushort4 o;
    o.x = f2bf(v.x); o.y = f2bf(v.y); o.z = f2bf(v.z); o.w = f2bf(v.w);
    reinterpret_cast<ushort4*>(out)[i] = o;
  }
}

// 4 weight matrices (same size) -> one contiguous bf16 region
__global__ void cvt4_kernel(const float* __restrict__ a, const float* __restrict__ b,
                           const float* __restrict__ c, const float* __restrict__ d,
                           unsigned short* __restrict__ out, int n4per) {
  const float* in = (blockIdx.y == 0) ? a : (blockIdx.y == 1) ? b : (blockIdx.y == 2) ? c : d;
  unsigned short* o = out + (size_t)blockIdx.y * (size_t)n4per * 4;
  int i = blockIdx.x * blockDim.x + threadIdx.x;
  int stride = gridDim.x * blockDim.x;
  for (; i < n4per; i += stride) {
    float4 v = reinterpret_cast<const float4*>(in)[i];
    ushort4 ov;
    ov.x = f2bf(v.x); ov.y = f2bf(v.y); ov.z = f2bf(v.z); ov.w = f2bf(v.w);
    reinterpret_cast<ushort4*>(o)[i] = ov;
  }
}

// ---------------- RoPE cos/sin tables: [TSEQ][64] fp32 ----------------
__global__ void rope_table_kernel(const int* __restrict__ pos, float* __restrict__ ctab, float* __restrict__ stab) {
  int idx = blockIdx.x * blockDim.x + threadIdx.x;  // t*64 + i
  if (idx >= TSEQ * 64) return;
  int i = idx & 63;
  int t = idx >> 6;
  float freq = expf(-(2.0f * i / 128.0f) * 9.210340371976184f);  // theta^-(2i/128)
  float ang = (float)pos[t] * freq;
  ctab[idx] = cosf(ang);
  stab[idx] = sinf(ang);
}

// ---------------- deep-pipelined GEMM (R10-proven 256x128 structure) ----------------
// MODE 0: C = A@Bt^T, f32 output [M][N].
// MODE 1: fused QKV epilogue. Bt = [Wq;Wk;Wv]:
//   sel 0/1 (Q/K): RoPE applied in-register (partner d^1 = lane lr^1 via
//     __shfl_xor), Q scaled by log2e/sqrt(d); written head-major [bh][t][d].
//   sel 2 (V): vtrans FUSED — acc -> LDS [d][t] (stride 264 shorts, 16B-aligned
//     rows), barrier, ds_read_b128 8 tokens/lane, coalesced V^T store.
#define G2M 256
#define G2N 128
#define G2K 64
template<int MODE>
__global__ __launch_bounds__(512, 2) void gemm256(
    const unsigned short* __restrict__ A,
    const unsigned short* __restrict__ Bt,
    void* __restrict__ Cp,
    unsigned short* __restrict__ QrO, unsigned short* __restrict__ KrO,
    const float* __restrict__ ct, const float* __restrict__ st,
    int K, int N, int NBN) {
  __shared__ unsigned short lds[3 * (G2M + G2N) * G2K];  // 147456 B
  const int t = threadIdx.x;
  const int lane = t & 63, w = t >> 6;      // 8 waves
  const int wr = w >> 2, wc = w & 3;        // 2 (M) x 4 (N)
  const int lr = lane & 15, lg = lane >> 4;
  const int nwg = gridDim.x;
  const int swz = (blockIdx.x & 7) * (nwg >> 3) + (blockIdx.x >> 3);
  const int m0 = (swz / NBN) * G2M;
  const int n0g = (swz % NBN) * G2N;
  const int NT = K / G2K;

  f32x4 acc[8][2] = {};

  auto stageA = [&](int kt, int b) {
    unsigned short* dst = &lds[b * (G2M + G2N) * G2K];
    const size_t k0 = (size_t)kt * G2K;
    #pragma unroll
    for (int c = 0; c < 4; c++) {
      int i = c * 512 + t;
      int row = i >> 3, slot = i & 7;
      int sslot = slot ^ (row & 7);
      GLOAD16(A + (size_t)(m0 + row) * K + k0 + sslot * 8,
              dst + (size_t)(c * 512 + w * 64) * 8);
    }
  };
  auto stageB = [&](int kt, int b) {
    unsigned short* dst = &lds[b * (G2M + G2N) * G2K + G2M * G2K];
    const size_t k0 = (size_t)kt * G2K;
    #pragma unroll
    for (int c = 0; c < 2; c++) {
      int i = c * 512 + t;
      int row = i >> 3, slot = i & 7;
      int sslot = slot ^ (row & 7);
      GLOAD16(Bt + (size_t)(n0g + row) * K + k0 + sslot * 8,
              dst + (size_t)(c * 512 + w * 64) * 8);
    }
  };

  const unsigned short* bufA = nullptr;
  const unsigned short* bufB = nullptr;
  auto ldA = [&](int mi, int ks) -> bf16x8 {
    int r = wr * 128 + mi * 16 + lr;
    int cb = (ks * 64 + lg * 16) ^ ((r & 7) << 4);
    return *(const bf16x8*)((const char*)bufA + r * 128 + cb);
  };
  auto ldB = [&](int ni, int ks) -> bf16x8 {
    int r = wc * 32 + ni * 16 + lr;
    int cb = (ks * 64 + lg * 16) ^ ((r & 7) << 4);
    return *(const bf16x8*)((const char*)bufB + r * 128 + cb);
  };

  stageA(0, 0); stageB(0, 0);
  stageA(1, 1); stageB(1, 1);

  for (int kt = 0; kt < NT; kt++) {
    if (kt + 1 < NT) { asm volatile("s_waitcnt vmcnt(6)" ::: "memory"); }
    else             { asm volatile("s_waitcnt vmcnt(0)" ::: "memory"); }
    __builtin_amdgcn_s_barrier();
    const int b = kt % 3;
    bufA = &lds[b * (G2M + G2N) * G2K];
    bufB = bufA + G2M * G2K;
    const int kt2 = kt + 2, b2 = kt2 % 3;

    bf16x8 bfr[2][2], afr[4][2];
    #pragma unroll
    for (int ni = 0; ni < 2; ni++)
      #pragma unroll
      for (int ks = 0; ks < 2; ks++) bfr[ni][ks] = ldB(ni, ks);
    #pragma unroll
    for (int mi = 0; mi < 4; mi++)
      #pragma unroll
      for (int ks = 0; ks < 2; ks++) afr[mi][ks] = ldA(mi, ks);
    if (kt2 < NT) stageA(kt2, b2);
    asm volatile("s_waitcnt lgkmcnt(0)" ::: "memory");
    __builtin_amdgcn_sched_barrier(0);
    __builtin_amdgcn_s_setprio(1);
    #pragma unroll
    for (int mi = 0; mi < 4; mi++)
      #pragma unroll
      for (int ni = 0; ni < 2; ni++)
        #pragma unroll
        for (int ks = 0; ks < 2; ks++)
          acc[mi][ni] = __builtin_amdgcn_mfma_f32_16x16x32_bf16(afr[mi][ks], bfr[ni][ks], acc[mi][ni], 0, 0, 0);
    __builtin_amdgcn_s_setprio(0);
    __builtin_amdgcn_s_barrier();

    bf16x8 afr2[4][2];
    #pragma unroll
    for (int mi = 0; mi < 4; mi++)
      #pragma unroll
      for (int ks = 0; ks < 2; ks++) afr2[mi][ks] = ldA(mi + 4, ks);
    if (kt2 < NT) stageB(kt2, b2);
    asm volatile("s_waitcnt lgkmcnt(0)" ::: "memory");
    __builtin_amdgcn_sched_barrier(0);
    __builtin_amdgcn_s_setprio(1);
    #pragma unroll
    for (int mi = 0; mi < 4; mi++)
      #pragma unroll
      for (int ni = 0; ni < 2; ni++)
        #pragma unroll
        for (int ks = 0; ks < 2; ks++)
          acc[mi + 4][ni] = __builtin_amdgcn_mfma_f32_16x16x32_bf16(afr2[mi][ks], bfr[ni][ks], acc[mi + 4][ni], 0, 0, 0);
    __builtin_amdgcn_s_setprio(0);
  }

  if (MODE == 0) {
    #pragma unroll
    for (int mi = 0; mi < 8; mi++)
      #pragma unroll
      for (int j = 0; j < 4; j++) {
        int row = m0 + wr * 128 + mi * 16 + lg * 4 + j;
        #pragma unroll
        for (int ni = 0; ni < 2; ni++) {
          int cg = n0g + wc * 32 + ni * 16 + lr;
          ((float*)Cp)[(size_t)row * N + cg] = acc[mi][ni][j];
        }
      }
  } else {
    const int sel = n0g >> 11;          // block-uniform: 0=Q 1=K 2=V
    if (sel == 2) {
      // fused V-transpose: one head panel (128 d x 256 t) per block
      __builtin_amdgcn_s_barrier();     // drain all waves' K-loop LDS reads
      unsigned short* Lt = lds;         // [128 d][264] shorts (528B rows, 16B-aligned)
      #pragma unroll
      for (int mi = 0; mi < 8; mi++)
        #pragma unroll
        for (int j = 0; j < 4; j++) {
          int tl = wr * 128 + mi * 16 + lg * 4 + j;
          #pragma unroll
          for (int ni = 0; ni < 2; ni++) {
            int d = wc * 32 + ni * 16 + lr;
            Lt[d * 264 + tl] = f2bf(acc[mi][ni][j]);
          }
        }
      __builtin_amdgcn_s_barrier();
      const int hh = (n0g & 2047) >> 7;
      const int bb = m0 >> 11, t0 = m0 & (TSEQ - 1);
      const int bh = bb * NH + hh;
      unsigned short* VtO = (unsigned short*)Cp;
      #pragma unroll
      for (int c = 0; c < 8; c++) {
        int ci = c * 512 + t;
        int d = ci >> 5, tc = ci & 31;
        bf16x8 v = *(const bf16x8*)&Lt[d * 264 + tc * 8];
        *(bf16x8*)&VtO[((size_t)bh * DHD + d) * TSEQ + t0 + tc * 8] = v;
      }
    } else {
      unsigned short* dst = sel ? KrO : QrO;
      const float qm = sel ? 1.0f : QSCALE;
      #pragma unroll
      for (int mi = 0; mi < 8; mi++)
        #pragma unroll
        for (int j = 0; j < 4; j++) {
          int row = m0 + wr * 128 + mi * 16 + lg * 4 + j;
          int bb = row >> 11, tt = row & (TSEQ - 1);
          #pragma unroll
          for (int ni = 0; ni < 2; ni++) {
            int c2 = (n0g + wc * 32 + ni * 16 + lr) & 2047;
            int d = c2 & 127, hh = c2 >> 7;
            float v = acc[mi][ni][j];
            float px = __shfl_xor(v, 1);
            float cc = ct[tt * 64 + (d >> 1)], ss = st[tt * 64 + (d >> 1)];
            float o = (d & 1) ? (px * ss + v * cc) : (v * cc - px * ss);
            dst[(((size_t)(bb * NH + hh)) * TSEQ + tt) * DHD + d] = f2bf(o * qm);
          }
        }
    }
  }
}

// ---------------- causal flash attention, 8-wave paired q-tiles (R10, best) ----------------
__global__ __launch_bounds__(512, 4) void attn_kernel(
    const unsigned short* __restrict__ Qr,
    const unsigned short* __restrict__ Kr,
    const unsigned short* __restrict__ VTt,
    unsigned short* __restrict__ Oa) {
  __shared__ unsigned short Ks[64 * 128];
  __shared__ unsigned short Vs[128 * 64];
  __shared__ unsigned short Ps[8 * 16 * 64];
  const int t = threadIdx.x;
  const int lane = t & 63, w = t >> 6;     // 8 waves
  const int wv = w & 3, half = w >> 2;     // half 0 = tile B, 1 = tile A
  const int lr = lane & 15, lg = lane >> 4;
  const int p = blockIdx.x, bh = blockIdx.y;
  const int qA = p, qB = 31 - p;           // qB > qA always (p in 0..15)
  const int myq = half ? qA : qB;
  const int q0 = myq * 64;
  const int nt = myq + 1;                  // my tile count
  const int ntB = qB + 1;                  // staging trip count
  const unsigned short* Qh = Qr + (size_t)bh * TSEQ * DHD;
  const unsigned short* Kh = Kr + (size_t)bh * TSEQ * DHD;
  const unsigned short* Vh = VTt + (size_t)bh * DHD * TSEQ;

  bf16x8 qf[4];
  #pragma unroll
  for (int ks = 0; ks < 4; ks++)
    qf[ks] = *(const bf16x8*)&Qh[((size_t)(q0 + wv * 16 + lr)) * DHD + ks * 32 + lg * 8];

  f32x4 oacc[8] = {};
  float ps[4] = {};
  unsigned short* Pw = &Ps[w * 16 * 64];

  for (int jt = 0; jt < ntB; jt++) {
    const int j0 = jt * 64;
    // stage K: [64 kv][128 d] -> 16 chunks/row (row = ci>>4, slot = ci&15)
    #pragma unroll
    for (int c = 0; c < 2; c++) {
      int ci = c * 512 + t;
      int row = ci >> 4, slot = ci & 15;
      GLOAD16(Kh + (size_t)(j0 + row) * DHD + (slot ^ (row & 7)) * 8,
              &Ks[(c * 512 + w * 64) * 8]);
    }
    // stage V: [128 d][64 t] -> 8 chunks/row (row = ci>>3, slot = ci&7)
    #pragma unroll
    for (int c = 0; c < 2; c++) {
      int ci = c * 512 + t;
      int row = ci >> 3, slot = ci & 7;
      GLOAD16(Vh + (size_t)row * TSEQ + j0 + (slot ^ (row & 7)) * 8,
              &Vs[(c * 512 + w * 64) * 8]);
    }
    __syncthreads();
    if (jt < nt) {
      const bool diag = (jt == nt - 1);
      f32x4 sv[4] = {};
      #pragma unroll
      for (int n = 0; n < 4; n++) {
        #pragma unroll
        for (int ks = 0; ks < 4; ks++) {
          int row = n * 16 + lr;
          int byteoff = row * 256 + (((ks * 64 + lg * 16)) ^ ((row & 7) << 4));
          bf16x8 kf = *(const bf16x8*)((const char*)Ks + byteoff);
          sv[n] = __builtin_amdgcn_mfma_f32_16x16x32_bf16(qf[ks], kf, sv[n], 0, 0, 0);
        }
      }
      if (diag) {
        #pragma unroll
        for (int n = 0; n < 4; n++) {
          int kcol = j0 + n * 16 + lr;
          #pragma unroll
          for (int j = 0; j < 4; j++)
            if (kcol > q0 + wv * 16 + lg * 4 + j) sv[n][j] = -INFINITY;
        }
      }
      #pragma unroll
      for (int n = 0; n < 4; n++) {
        #pragma unroll
        for (int j = 0; j < 4; j++) {
          float pv = exp2f(sv[n][j]);
          ps[j] += pv;
          int prow = lg * 4 + j;
          int pcol = n * 16 + lr;
          int byteoff = (prow * 128 + pcol * 2) ^ ((prow & 7) << 4);
          *(unsigned short*)((char*)Pw + byteoff) = f2bf(pv);
        }
      }
      bf16x8 pa[2];
      #pragma unroll
      for (int kk = 0; kk < 2; kk++) {
        int byteoff = lr * 128 + (((kk * 64 + lg * 16)) ^ ((lr & 7) << 4));
        pa[kk] = *(const bf16x8*)((const char*)Pw + byteoff);
      }
      #pragma unroll
      for (int n2 = 0; n2 < 8; n2++) {
        #pragma unroll
        for (int kk = 0; kk < 2; kk++) {
          int row = n2 * 16 + lr;
          int byteoff = row * 128 + (((kk * 64 + lg * 16)) ^ ((row & 7) << 4));
          bf16x8 vf = *(const bf16x8*)((const char*)Vs + byteoff);
          oacc[n2] = __builtin_amdgcn_mfma_f32_16x16x32_bf16(pa[kk], vf, oacc[n2], 0, 0, 0);
        }
      }
    }
    __syncthreads();
  }

  #pragma unroll
  for (int m = 1; m < 16; m <<= 1)
    #pragma unroll
    for (int j = 0; j < 4; j++) ps[j] += __shfl_xor(ps[j], m);
  const int h = bh & (NH - 1), b = bh >> 4;
  #pragma unroll
  for (int j = 0; j < 4; j++) {
    float inv = 1.0f / ps[j];
    int tt = q0 + wv * 16 + lg * 4 + j;
    size_t base = ((size_t)(b * TSEQ + tt)) * DM + h * DHD;
    #pragma unroll
    for (int n2 = 0; n2 < 8; n2++)
      Oa[base + n2 * 16 + lr] = f2bf(oacc[n2][j] * inv);
  }
}

// ---------------- launch ----------------
extern "C" void kernel_launch(void* const* d_in, const int* in_sizes, int n_in,
                              void* d_out, int out_size, void* d_ws, size_t ws_size,
                              hipStream_t stream) {
  const float* x  = (const float*)d_in[0];
  const int*   pos = (const int*)d_in[1];
  const float* Wq = (const float*)d_in[2];
  const float* Wk = (const float*)d_in[3];
  const float* Wv = (const float*)d_in[4];
  const float* Wp = (const float*)d_in[5];
  float* out = (float*)d_out;

  char* wsp = (char*)d_ws;
  auto alloc = [&](size_t bytes) { char* p = wsp; wsp += (bytes + 255) & ~(size_t)255; return p; };
  unsigned short* xb  = (unsigned short*)alloc((size_t)NTOK * DM * 2);  // x; later Oa
  unsigned short* wqb = (unsigned short*)alloc((size_t)DM * DM * 2);    // wq/wk/wv/wp contiguous
  unsigned short* wkb = (unsigned short*)alloc((size_t)DM * DM * 2);
  unsigned short* wvb = (unsigned short*)alloc((size_t)DM * DM * 2);
  unsigned short* wpb = (unsigned short*)alloc((size_t)DM * DM * 2);
  unsigned short* Qb  = (unsigned short*)alloc((size_t)NTOK * DM * 2);  // roped Q, head-major
  unsigned short* Kb  = (unsigned short*)alloc((size_t)NTOK * DM * 2);  // roped K, head-major
  unsigned short* VTt = (unsigned short*)alloc((size_t)NTOK * DM * 2);  // V^T head-major (direct)
  float* ctab = (float*)alloc((size_t)TSEQ * 64 * 4);
  float* stab = (float*)alloc((size_t)TSEQ * 64 * 4);
  unsigned short* Oa = xb;   // x dead after QKV projection
  (void)wkb; (void)wvb;

  int n4x = NTOK * DM / 4, n4w = DM * DM / 4;
  cvt_kernel<<<2048, 256, 0, stream>>>(x, xb, n4x);
  cvt4_kernel<<<dim3(256, 4), 256, 0, stream>>>(Wq, Wk, Wv, Wp, wqb, n4w);
  rope_table_kernel<<<(TSEQ * 64) / 256, 256, 0, stream>>>(pos, ctab, stab);

  // fused QKV projection + RoPE + V-transpose epilogue: grid 16x48 = 768
  gemm256<1><<<(NTOK / G2M) * (3 * DM / G2N), 512, 0, stream>>>(
      xb, wqb, VTt, Qb, Kb, ctab, stab, DM, DM, 3 * DM / G2N);

  // attention: paired q-tiles, 512 blocks (R10-proven)
  attn_kernel<<<dim3(16, NBB * NH), 512, 0, stream>>>(Qb, Kb, VTt, Oa);

  // output projection: 256-block gemm256, 1 block/CU = all CUs busy
  gemm256<0><<<(NTOK / G2M) * (DM / G2N), 512, 0, stream>>>(
      Oa, wpb, out, nullptr, nullptr, nullptr, nullptr, DM, DM, DM / G2N);
}

// Round 15
// 238.921 us; speedup vs baseline: 1.0893x; 1.0088x over previous
//
#include <hip/hip_runtime.h>
#include <hip/hip_bf16.h>

#define DM    2048
#define NH    16
#define DHD   128
#define TSEQ  2048
#define NBB   2
#define NTOK  (NBB*TSEQ)   // 4096

typedef __attribute__((ext_vector_type(8))) short bf16x8;
typedef __attribute__((ext_vector_type(4))) float f32x4;

typedef __attribute__((address_space(1))) const void GVoid;
typedef __attribute__((address_space(3))) void LVoid;
#define GLOAD16(SRC, DST) __builtin_amdgcn_global_load_lds((GVoid*)(SRC), (LVoid*)(DST), 16, 0, 0)

// branchless round-to-nearest-even bf16 (no NaN path; data has no NaNs).
__device__ __forceinline__ unsigned short f2bf(float f) {
  union { float f; unsigned u; } v; v.f = f;
  unsigned r = v.u + 0x7fffu + ((v.u >> 16) & 1u);
  return (unsigned short)(r >> 16);
}
__device__ __forceinline__ float bf2f(unsigned short h) {
  union { unsigned u; float f; } v; v.u = ((unsigned)h) << 16;
  return v.f;
}

#define QSCALE (0.08838834764831845f * 1.4426950408889634f)  // log2e/sqrt(128)

// ---------------- fp32 -> bf16 convert ----------------
__global__ void cvt_kernel(const float* __restrict__ in, unsigned short* __restrict__ out, int n4) {
  int i = blockIdx.x * blockDim.x + threadIdx.x;
  int stride = gridDim.x * blockDim.x;
  for (; i < n4; i += stride) {
    float4 v = reinterpret_cast<const float4*>(in)[i];
    ushort4 o;
    o.x = f2bf(v.x); o.y = f2bf(v.y); o.z = f2bf(v.z); o.w = f2bf(v.w);
    reinterpret_cast<ushort4*>(out)[i] = o;
  }
}

// 4 weight matrices (same size) -> one contiguous bf16 region
__global__ void cvt4_kernel(const float* __restrict__ a, const float* __restrict__ b,
                           const float* __restrict__ c, const float* __restrict__ d,
                           unsigned short* __restrict__ out, int n4per) {
  const float* in = (blockIdx.y == 0) ? a : (blockIdx.y == 1) ? b : (blockIdx.y == 2) ? c : d;
  unsigned short* o = out + (size_t)blockIdx.y * (size_t)n4per * 4;
  int i = blockIdx.x * blockDim.x + threadIdx.x;
  int stride = gridDim.x * blockDim.x;
  for (; i < n4per; i += stride) {
    float4 v = reinterpret_cast<const float4*>(in)[i];
    ushort4 ov;
    ov.x = f2bf(v.x); ov.y = f2bf(v.y); ov.z = f2bf(v.z); ov.w = f2bf(v.w);
    reinterpret_cast<ushort4*>(o)[i] = ov;
  }
}

// ---------------- RoPE cos/sin tables: [TSEQ][64] fp32 ----------------
__global__ void rope_table_kernel(const int* __restrict__ pos, float* __restrict__ ctab, float* __restrict__ stab) {
  int idx = blockIdx.x * blockDim.x + threadIdx.x;  // t*64 + i
  if (idx >= TSEQ * 64) return;
  int i = idx & 63;
  int t = idx >> 6;
  float freq = expf(-(2.0f * i / 128.0f) * 9.210340371976184f);  // theta^-(2i/128)
  float ang = (float)pos[t] * freq;
  ctab[idx] = cosf(ang);
  stab[idx] = sinf(ang);
}

// ---------------- gemmsq: 256x256 tile, BK=32 — high FLOP/LDS-byte ----------------
// Rationale: at 256x128/BK=64, LDS re-read traffic (A x4, B x2 replication) is
// 21.8 FLOP/byte -> LDS-pipe-bound at MfmaUtil 39%. 256x256 doubles to 43.6.
// BK=32 => 64B rows: a wave's frag read (16 rows x 4 chunks) is a contiguous
// 1KB block -> conflict-free, NO swizzle needed. 4 buffers x 32KB = 128 KB,
// depth-2 prefetch, counted vmcnt(4) (tile t+1's 4 loads in flight, never 0).
// Race-free: stage (t+2)&3 overwrites tile t-2, last read 2 barriers ago.
// ROPE epilogue: Bt = [Wq;Wk], sel by n0g>=2048; Q scaled, K plain, head-major.
#define QM  256
#define QN  256
#define QKS 32
#define QLDSB ((QM + QN) * QKS)   // 16384 shorts = 32 KB
__global__ __launch_bounds__(512, 2) void gemmsq(
    const unsigned short* __restrict__ A,
    const unsigned short* __restrict__ Bt,
    unsigned short* __restrict__ QrO, unsigned short* __restrict__ KrO,
    const float* __restrict__ ct, const float* __restrict__ st,
    int K, int NBN) {
  __shared__ unsigned short lds[4 * QLDSB];  // 131072 B
  const int t = threadIdx.x;
  const int lane = t & 63, w = t >> 6;       // 8 waves
  const int wr = w >> 2, wc = w & 3;         // 2 (M) x 4 (N)
  const int lr = lane & 15, lg = lane >> 4;
  const int nwg = gridDim.x;
  const int swz = (blockIdx.x & 7) * (nwg >> 3) + (blockIdx.x >> 3);
  const int m0 = (swz / NBN) * QM;
  const int n0g = (swz % NBN) * QN;
  const int NT = K / QKS;                    // 64

  f32x4 acc[8][4] = {};                      // 128 VGPR

  // A: 256 rows x 32 k = 1024 x 16B chunks over 512 thr (2 each); linear LDS.
  auto stageA = [&](int kt, int b) {
    unsigned short* dst = &lds[b * QLDSB];
    const size_t k0 = (size_t)kt * QKS;
    #pragma unroll
    for (int c = 0; c < 2; c++) {
      int ci = c * 512 + t;
      int row = ci >> 2, slot = ci & 3;
      GLOAD16(A + (size_t)(m0 + row) * K + k0 + slot * 8,
              dst + (size_t)(c * 512 + w * 64) * 8);
    }
  };
  auto stageB = [&](int kt, int b) {
    unsigned short* dst = &lds[b * QLDSB + QM * QKS];
    const size_t k0 = (size_t)kt * QKS;
    #pragma unroll
    for (int c = 0; c < 2; c++) {
      int ci = c * 512 + t;
      int row = ci >> 2, slot = ci & 3;
      GLOAD16(Bt + (size_t)(n0g + row) * K + k0 + slot * 8,
              dst + (size_t)(c * 512 + w * 64) * 8);
    }
  };

  const unsigned short* buf = nullptr;
  auto ldA = [&](int mi) -> bf16x8 {
    int r = wr * 128 + mi * 16 + lr;
    return *(const bf16x8*)((const char*)buf + r * 64 + lg * 16);
  };
  auto ldB = [&](int ni) -> bf16x8 {
    int r = wc * 64 + ni * 16 + lr;
    return *(const bf16x8*)((const char*)(buf + QM * QKS) + r * 64 + lg * 16);
  };

  stageA(0, 0); stageB(0, 0);
  stageA(1, 1); stageB(1, 1);

  for (int kt = 0; kt < NT; kt++) {
    if (kt + 1 < NT) { asm volatile("s_waitcnt vmcnt(4)" ::: "memory"); }
    else             { asm volatile("s_waitcnt vmcnt(0)" ::: "memory"); }
    __builtin_amdgcn_s_barrier();
    buf = &lds[(kt & 3) * QLDSB];
    const int kt2 = kt + 2, b2 = kt2 & 3;

    // phase 1: B-frags (held) + A mi 0-3
    bf16x8 bfr[4], afr[4];
    #pragma unroll
    for (int ni = 0; ni < 4; ni++) bfr[ni] = ldB(ni);
    #pragma unroll
    for (int mi = 0; mi < 4; mi++) afr[mi] = ldA(mi);
    if (kt2 < NT) stageA(kt2, b2);
    asm volatile("s_waitcnt lgkmcnt(0)" ::: "memory");
    __builtin_amdgcn_sched_barrier(0);
    __builtin_amdgcn_s_setprio(1);
    #pragma unroll
    for (int mi = 0; mi < 4; mi++)
      #pragma unroll
      for (int ni = 0; ni < 4; ni++)
        acc[mi][ni] = __builtin_amdgcn_mfma_f32_16x16x32_bf16(afr[mi], bfr[ni], acc[mi][ni], 0, 0, 0);
    __builtin_amdgcn_s_setprio(0);
    __builtin_amdgcn_s_barrier();

    // phase 2: A mi 4-7
    bf16x8 afr2[4];
    #pragma unroll
    for (int mi = 0; mi < 4; mi++) afr2[mi] = ldA(mi + 4);
    if (kt2 < NT) stageB(kt2, b2);
    asm volatile("s_waitcnt lgkmcnt(0)" ::: "memory");
    __builtin_amdgcn_sched_barrier(0);
    __builtin_amdgcn_s_setprio(1);
    #pragma unroll
    for (int mi = 0; mi < 4; mi++)
      #pragma unroll
      for (int ni = 0; ni < 4; ni++)
        acc[mi + 4][ni] = __builtin_amdgcn_mfma_f32_16x16x32_bf16(afr2[mi], bfr[ni], acc[mi + 4][ni], 0, 0, 0);
    __builtin_amdgcn_s_setprio(0);
  }

  // RoPE epilogue: sel 0=Q (scaled), 1=K; head-major [bh][t][d].
  const int selK = n0g >> 11;
  unsigned short* dst = selK ? KrO : QrO;
  const float qm = selK ? 1.0f : QSCALE;
  #pragma unroll
  for (int mi = 0; mi < 8; mi++)
    #pragma unroll
    for (int j = 0; j < 4; j++) {
      int row = m0 + wr * 128 + mi * 16 + lg * 4 + j;
      int bb = row >> 11, tt = row & (TSEQ - 1);
      #pragma unroll
      for (int ni = 0; ni < 4; ni++) {
        int c2 = (n0g + wc * 64 + ni * 16 + lr) & 2047;
        int d = c2 & 127, hh = c2 >> 7;
        float v = acc[mi][ni][j];
        float px = __shfl_xor(v, 1);   // rotary partner: col d^1 = lane lr^1
        float cc = ct[tt * 64 + (d >> 1)], ss = st[tt * 64 + (d >> 1)];
        float o = (d & 1) ? (px * ss + v * cc) : (v * cc - px * ss);
        dst[(((size_t)(bb * NH + hh)) * TSEQ + tt) * DHD + d] = f2bf(o * qm);
      }
    }
}

// ---------------- gemm256: 256x128/BK=64 (R10-proven) ----------------
// MODE 0: C = A@Bt^T, f32 [M][N] (proj). MODE 2: V-GEMM + fused V-transpose
// (one head panel 128d x 256t per block -> V^T head-major).
#define G2M 256
#define G2N 128
#define G2K 64
template<int MODE>
__global__ __launch_bounds__(512, 2) void gemm256(
    const unsigned short* __restrict__ A,
    const unsigned short* __restrict__ Bt,
    void* __restrict__ Cp, int K, int N, int NBN) {
  __shared__ unsigned short lds[3 * (G2M + G2N) * G2K];  // 147456 B
  const int t = threadIdx.x;
  const int lane = t & 63, w = t >> 6;
  const int wr = w >> 2, wc = w & 3;
  const int lr = lane & 15, lg = lane >> 4;
  const int nwg = gridDim.x;
  const int swz = (blockIdx.x & 7) * (nwg >> 3) + (blockIdx.x >> 3);
  const int m0 = (swz / NBN) * G2M;
  const int n0g = (swz % NBN) * G2N;
  const int NT = K / G2K;

  f32x4 acc[8][2] = {};

  auto stageA = [&](int kt, int b) {
    unsigned short* dst = &lds[b * (G2M + G2N) * G2K];
    const size_t k0 = (size_t)kt * G2K;
    #pragma unroll
    for (int c = 0; c < 4; c++) {
      int i = c * 512 + t;
      int row = i >> 3, slot = i & 7;
      int sslot = slot ^ (row & 7);
      GLOAD16(A + (size_t)(m0 + row) * K + k0 + sslot * 8,
              dst + (size_t)(c * 512 + w * 64) * 8);
    }
  };
  auto stageB = [&](int kt, int b) {
    unsigned short* dst = &lds[b * (G2M + G2N) * G2K + G2M * G2K];
    const size_t k0 = (size_t)kt * G2K;
    #pragma unroll
    for (int c = 0; c < 2; c++) {
      int i = c * 512 + t;
      int row = i >> 3, slot = i & 7;
      int sslot = slot ^ (row & 7);
      GLOAD16(Bt + (size_t)(n0g + row) * K + k0 + sslot * 8,
              dst + (size_t)(c * 512 + w * 64) * 8);
    }
  };

  const unsigned short* bufA = nullptr;
  const unsigned short* bufB = nullptr;
  auto ldA = [&](int mi, int ks) -> bf16x8 {
    int r = wr * 128 + mi * 16 + lr;
    int cb = (ks * 64 + lg * 16) ^ ((r & 7) << 4);
    return *(const bf16x8*)((const char*)bufA + r * 128 + cb);
  };
  auto ldB = [&](int ni, int ks) -> bf16x8 {
    int r = wc * 32 + ni * 16 + lr;
    int cb = (ks * 64 + lg * 16) ^ ((r & 7) << 4);
    return *(const bf16x8*)((const char*)bufB + r * 128 + cb);
  };

  stageA(0, 0); stageB(0, 0);
  stageA(1, 1); stageB(1, 1);

  for (int kt = 0; kt < NT; kt++) {
    if (kt + 1 < NT) { asm volatile("s_waitcnt vmcnt(6)" ::: "memory"); }
    else             { asm volatile("s_waitcnt vmcnt(0)" ::: "memory"); }
    __builtin_amdgcn_s_barrier();
    const int b = kt % 3;
    bufA = &lds[b * (G2M + G2N) * G2K];
    bufB = bufA + G2M * G2K;
    const int kt2 = kt + 2, b2 = kt2 % 3;

    bf16x8 bfr[2][2], afr[4][2];
    #pragma unroll
    for (int ni = 0; ni < 2; ni++)
      #pragma unroll
      for (int ks = 0; ks < 2; ks++) bfr[ni][ks] = ldB(ni, ks);
    #pragma unroll
    for (int mi = 0; mi < 4; mi++)
      #pragma unroll
      for (int ks = 0; ks < 2; ks++) afr[mi][ks] = ldA(mi, ks);
    if (kt2 < NT) stageA(kt2, b2);
    asm volatile("s_waitcnt lgkmcnt(0)" ::: "memory");
    __builtin_amdgcn_sched_barrier(0);
    __builtin_amdgcn_s_setprio(1);
    #pragma unroll
    for (int mi = 0; mi < 4; mi++)
      #pragma unroll
      for (int ni = 0; ni < 2; ni++)
        #pragma unroll
        for (int ks = 0; ks < 2; ks++)
          acc[mi][ni] = __builtin_amdgcn_mfma_f32_16x16x32_bf16(afr[mi][ks], bfr[ni][ks], acc[mi][ni], 0, 0, 0);
    __builtin_amdgcn_s_setprio(0);
    __builtin_amdgcn_s_barrier();

    bf16x8 afr2[4][2];
    #pragma unroll
    for (int mi = 0; mi < 4; mi++)
      #pragma unroll
      for (int ks = 0; ks < 2; ks++) afr2[mi][ks] = ldA(mi + 4, ks);
    if (kt2 < NT) stageB(kt2, b2);
    asm volatile("s_waitcnt lgkmcnt(0)" ::: "memory");
    __builtin_amdgcn_sched_barrier(0);
    __builtin_amdgcn_s_setprio(1);
    #pragma unroll
    for (int mi = 0; mi < 4; mi++)
      #pragma unroll
      for (int ni = 0; ni < 2; ni++)
        #pragma unroll
        for (int ks = 0; ks < 2; ks++)
          acc[mi + 4][ni] = __builtin_amdgcn_mfma_f32_16x16x32_bf16(afr2[mi][ks], bfr[ni][ks], acc[mi + 4][ni], 0, 0, 0);
    __builtin_amdgcn_s_setprio(0);
  }

  if (MODE == 0) {
    #pragma unroll
    for (int mi = 0; mi < 8; mi++)
      #pragma unroll
      for (int j = 0; j < 4; j++) {
        int row = m0 + wr * 128 + mi * 16 + lg * 4 + j;
        #pragma unroll
        for (int ni = 0; ni < 2; ni++) {
          int cg = n0g + wc * 32 + ni * 16 + lr;
          ((float*)Cp)[(size_t)row * N + cg] = acc[mi][ni][j];
        }
      }
  } else {
    // fused V-transpose: one head panel (128 d x 256 t) per block
    __builtin_amdgcn_s_barrier();     // drain all waves' K-loop LDS reads
    unsigned short* Lt = lds;         // [128 d][264] shorts (528B rows)
    #pragma unroll
    for (int mi = 0; mi < 8; mi++)
      #pragma unroll
      for (int j = 0; j < 4; j++) {
        int tl = wr * 128 + mi * 16 + lg * 4 + j;
        #pragma unroll
        for (int ni = 0; ni < 2; ni++) {
          int d = wc * 32 + ni * 16 + lr;
          Lt[d * 264 + tl] = f2bf(acc[mi][ni][j]);
        }
      }
    __builtin_amdgcn_s_barrier();
    const int hh = n0g >> 7;
    const int bb = m0 >> 11, t0 = m0 & (TSEQ - 1);
    const int bh = bb * NH + hh;
    unsigned short* VtO = (unsigned short*)Cp;
    #pragma unroll
    for (int c = 0; c < 8; c++) {
      int ci = c * 512 + t;
      int d = ci >> 5, tc = ci & 31;
      bf16x8 v = *(const bf16x8*)&Lt[d * 264 + tc * 8];
      *(bf16x8*)&VtO[((size_t)bh * DHD + d) * TSEQ + t0 + tc * 8] = v;
    }
  }
}

// ---------------- causal flash attention, 8-wave paired q-tiles (R10, best) ----------------
__global__ __launch_bounds__(512, 4) void attn_kernel(
    const unsigned short* __restrict__ Qr,
    const unsigned short* __restrict__ Kr,
    const unsigned short* __restrict__ VTt,
    unsigned short* __restrict__ Oa) {
  __shared__ unsigned short Ks[64 * 128];
  __shared__ unsigned short Vs[128 * 64];
  __shared__ unsigned short Ps[8 * 16 * 64];
  const int t = threadIdx.x;
  const int lane = t & 63, w = t >> 6;     // 8 waves
  const int wv = w & 3, half = w >> 2;     // half 0 = tile B, 1 = tile A
  const int lr = lane & 15, lg = lane >> 4;
  const int p = blockIdx.x, bh = blockIdx.y;
  const int qA = p, qB = 31 - p;           // qB > qA always (p in 0..15)
  const int myq = half ? qA : qB;
  const int q0 = myq * 64;
  const int nt = myq + 1;                  // my tile count
  const int ntB = qB + 1;                  // staging trip count
  const unsigned short* Qh = Qr + (size_t)bh * TSEQ * DHD;
  const unsigned short* Kh = Kr + (size_t)bh * TSEQ * DHD;
  const unsigned short* Vh = VTt + (size_t)bh * DHD * TSEQ;

  bf16x8 qf[4];
  #pragma unroll
  for (int ks = 0; ks < 4; ks++)
    qf[ks] = *(const bf16x8*)&Qh[((size_t)(q0 + wv * 16 + lr)) * DHD + ks * 32 + lg * 8];

  f32x4 oacc[8] = {};
  float ps[4] = {};
  unsigned short* Pw = &Ps[w * 16 * 64];

  for (int jt = 0; jt < ntB; jt++) {
    const int j0 = jt * 64;
    #pragma unroll
    for (int c = 0; c < 2; c++) {
      int ci = c * 512 + t;
      int row = ci >> 4, slot = ci & 15;
      GLOAD16(Kh + (size_t)(j0 + row) * DHD + (slot ^ (row & 7)) * 8,
              &Ks[(c * 512 + w * 64) * 8]);
    }
    #pragma unroll
    for (int c = 0; c < 2; c++) {
      int ci = c * 512 + t;
      int row = ci >> 3, slot = ci & 7;
      GLOAD16(Vh + (size_t)row * TSEQ + j0 + (slot ^ (row & 7)) * 8,
              &Vs[(c * 512 + w * 64) * 8]);
    }
    __syncthreads();
    if (jt < nt) {
      const bool diag = (jt == nt - 1);
      f32x4 sv[4] = {};
      #pragma unroll
      for (int n = 0; n < 4; n++) {
        #pragma unroll
        for (int ks = 0; ks < 4; ks++) {
          int row = n * 16 + lr;
          int byteoff = row * 256 + (((ks * 64 + lg * 16)) ^ ((row & 7) << 4));
          bf16x8 kf = *(const bf16x8*)((const char*)Ks + byteoff);
          sv[n] = __builtin_amdgcn_mfma_f32_16x16x32_bf16(qf[ks], kf, sv[n], 0, 0, 0);
        }
      }
      if (diag) {
        #pragma unroll
        for (int n = 0; n < 4; n++) {
          int kcol = j0 + n * 16 + lr;
          #pragma unroll
          for (int j = 0; j < 4; j++)
            if (kcol > q0 + wv * 16 + lg * 4 + j) sv[n][j] = -INFINITY;
        }
      }
      #pragma unroll
      for (int n = 0; n < 4; n++) {
        #pragma unroll
        for (int j = 0; j < 4; j++) {
          float pv = exp2f(sv[n][j]);
          ps[j] += pv;
          int prow = lg * 4 + j;
          int pcol = n * 16 + lr;
          int byteoff = (prow * 128 + pcol * 2) ^ ((prow & 7) << 4);
          *(unsigned short*)((char*)Pw + byteoff) = f2bf(pv);
        }
      }
      bf16x8 pa[2];
      #pragma unroll
      for (int kk = 0; kk < 2; kk++) {
        int byteoff = lr * 128 + (((kk * 64 + lg * 16)) ^ ((lr & 7) << 4));
        pa[kk] = *(const bf16x8*)((const char*)Pw + byteoff);
      }
      #pragma unroll
      for (int n2 = 0; n2 < 8; n2++) {
        #pragma unroll
        for (int kk = 0; kk < 2; kk++) {
          int row = n2 * 16 + lr;
          int byteoff = row * 128 + (((kk * 64 + lg * 16)) ^ ((row & 7) << 4));
          bf16x8 vf = *(const bf16x8*)((const char*)Vs + byteoff);
          oacc[n2] = __builtin_amdgcn_mfma_f32_16x16x32_bf16(pa[kk], vf, oacc[n2], 0, 0, 0);
        }
      }
    }
    __syncthreads();
  }

  #pragma unroll
  for (int m = 1; m < 16; m <<= 1)
    #pragma unroll
    for (int j = 0; j < 4; j++) ps[j] += __shfl_xor(ps[j], m);
  const int h = bh & (NH - 1), b = bh >> 4;
  #pragma unroll
  for (int j = 0; j < 4; j++) {
    float inv = 1.0f / ps[j];
    int tt = q0 + wv * 16 + lg * 4 + j;
    size_t base = ((size_t)(b * TSEQ + tt)) * DM + h * DHD;
    #pragma unroll
    for (int n2 = 0; n2 < 8; n2++)
      Oa[base + n2 * 16 + lr] = f2bf(oacc[n2][j] * inv);
  }
}

// ---------------- launch ----------------
extern "C" void kernel_launch(void* const* d_in, const int* in_sizes, int n_in,
                              void* d_out, int out_size, void* d_ws, size_t ws_size,
                              hipStream_t stream) {
  const float* x  = (const float*)d_in[0];
  const int*   pos = (const int*)d_in[1];
  const float* Wq = (const float*)d_in[2];
  const float* Wk = (const float*)d_in[3];
  const float* Wv = (const float*)d_in[4];
  const float* Wp = (const float*)d_in[5];
  float* out = (float*)d_out;

  char* wsp = (char*)d_ws;
  auto alloc = [&](size_t bytes) { char* p = wsp; wsp += (bytes + 255) & ~(size_t)255; return p; };
  unsigned short* xb  = (unsigned short*)alloc((size_t)NTOK * DM * 2);  // x; later Oa
  unsigned short* wqb = (unsigned short*)alloc((size_t)DM * DM * 2);    // wq/wk/wv/wp contiguous
  unsigned short* wkb = (unsigned short*)alloc((size_t)DM * DM * 2);
  unsigned short* wvb = (unsigned short*)alloc((size_t)DM * DM * 2);
  unsigned short* wpb = (unsigned short*)alloc((size_t)DM * DM * 2);
  unsigned short* Qb  = (unsigned short*)alloc((size_t)NTOK * DM * 2);  // roped Q, head-major
  unsigned short* Kb  = (unsigned short*)alloc((size_t)NTOK * DM * 2);  // roped K, head-major
  unsigned short* VTt = (unsigned short*)alloc((size_t)NTOK * DM * 2);  // V^T head-major (direct)
  float* ctab = (float*)alloc((size_t)TSEQ * 64 * 4);
  float* stab = (float*)alloc((size_t)TSEQ * 64 * 4);
  unsigned short* Oa = xb;   // x dead after QKV projection
  (void)wkb;

  int n4x = NTOK * DM / 4, n4w = DM * DM / 4;
  cvt_kernel<<<2048, 256, 0, stream>>>(x, xb, n4x);
  cvt4_kernel<<<dim3(256, 4), 256, 0, stream>>>(Wq, Wk, Wv, Wp, wqb, n4w);
  rope_table_kernel<<<(TSEQ * 64) / 256, 256, 0, stream>>>(pos, ctab, stab);

  // QK projection + RoPE epilogue: Bt = [Wq;Wk] (N=4096), grid 16x16 = 256 (1 round)
  gemmsq<<<(NTOK / QM) * (2 * DM / QN), 512, 0, stream>>>(
      xb, wqb, Qb, Kb, ctab, stab, DM, 2 * DM / QN);

  // V projection + fused V-transpose: grid 16x16 = 256 (1 round)
  gemm256<2><<<(NTOK / G2M) * (DM / G2N), 512, 0, stream>>>(
      xb, wvb, VTt, DM, DM, DM / G2N);

  // attention: paired q-tiles, 512 blocks (R10-proven)
  attn_kernel<<<dim3(16, NBB * NH), 512, 0, stream>>>(Qb, Kb, VTt, Oa);

  // output projection: 256-block gemm256, 1 block/CU = all CUs busy
  gemm256<0><<<(NTOK / G2M) * (DM / G2N), 512, 0, stream>>>(
      Oa, wpb, out, DM, DM, DM / G2N);
}

// Round 16
// 232.134 us; speedup vs baseline: 1.1212x; 1.0292x over previous
//
#include <hip/hip_runtime.h>
#include <hip/hip_bf16.h>

#define DM    2048
#define NH    16
#define DHD   128
#define TSEQ  2048
#define NBB   2
#define NTOK  (NBB*TSEQ)   // 4096

typedef __attribute__((ext_vector_type(8))) short bf16x8;
typedef __attribute__((ext_vector_type(4))) float f32x4;

typedef __attribute__((address_space(1))) const void GVoid;
typedef __attribute__((address_space(3))) void LVoid;
#define GLOAD16(SRC, DST) __builtin_amdgcn_global_load_lds((GVoid*)(SRC), (LVoid*)(DST), 16, 0, 0)

// branchless round-to-nearest-even bf16 (no NaN path; data has no NaNs).
__device__ __forceinline__ unsigned short f2bf(float f) {
  union { float f; unsigned u; } v; v.f = f;
  unsigned r = v.u + 0x7fffu + ((v.u >> 16) & 1u);
  return (unsigned short)(r >> 16);
}
__device__ __forceinline__ float bf2f(unsigned short h) {
  union { unsigned u; float f; } v; v.u = ((unsigned)h) << 16;
  return v.f;
}

#define QSCALE (0.08838834764831845f * 1.4426950408889634f)  // log2e/sqrt(128)

// ---------------- fp32 -> bf16 convert ----------------
__global__ void cvt_kernel(const float* __restrict__ in, unsigned short* __restrict__ out, int n4) {
  int i = blockIdx.x * blockDim.x + threadIdx.x;
  int stride = gridDim.x * blockDim.x;
  for (; i < n4; i += stride) {
    float4 v = reinterpret_cast<const float4*>(in)[i];
    ushort4 o;
    o.x = f2bf(v.x); o.y = f2bf(v.y); o.z = f2bf(v.z); o.w = f2bf(v.w);
    reinterpret_cast<ushort4*>(out)[i] = o;
  }
}

// 4 weight matrices (same size) -> one contiguous bf16 region
__global__ void cvt4_kernel(const float* __restrict__ a, const float* __restrict__ b,
                           const float* __restrict__ c, const float* __restrict__ d,
                           unsigned short* __restrict__ out, int n4per) {
  const float* in = (blockIdx.y == 0) ? a : (blockIdx.y == 1) ? b : (blockIdx.y == 2) ? c : d;
  unsigned short* o = out + (size_t)blockIdx.y * (size_t)n4per * 4;
  int i = blockIdx.x * blockDim.x + threadIdx.x;
  int stride = gridDim.x * blockDim.x;
  for (; i < n4per; i += stride) {
    float4 v = reinterpret_cast<const float4*>(in)[i];
    ushort4 ov;
    ov.x = f2bf(v.x); ov.y = f2bf(v.y); ov.z = f2bf(v.z); ov.w = f2bf(v.w);
    reinterpret_cast<ushort4*>(o)[i] = ov;
  }
}

// ---------------- RoPE cos/sin tables: [TSEQ][64] fp32 ----------------
__global__ void rope_table_kernel(const int* __restrict__ pos, float* __restrict__ ctab, float* __restrict__ stab) {
  int idx = blockIdx.x * blockDim.x + threadIdx.x;  // t*64 + i
  if (idx >= TSEQ * 64) return;
  int i = idx & 63;
  int t = idx >> 6;
  float freq = expf(-(2.0f * i / 128.0f) * 9.210340371976184f);  // theta^-(2i/128)
  float ang = (float)pos[t] * freq;
  ctab[idx] = cosf(ang);
  stab[idx] = sinf(ang);
}

// ---------------- gemmsq: 256x256 tile, BK=32 — high FLOP/LDS-byte ----------------
#define QM  256
#define QN  256
#define QKS 32
#define QLDSB ((QM + QN) * QKS)   // 16384 shorts = 32 KB
__global__ __launch_bounds__(512, 2) void gemmsq(
    const unsigned short* __restrict__ A,
    const unsigned short* __restrict__ Bt,
    unsigned short* __restrict__ QrO, unsigned short* __restrict__ KrO,
    const float* __restrict__ ct, const float* __restrict__ st,
    int K, int NBN) {
  __shared__ unsigned short lds[4 * QLDSB];  // 131072 B
  const int t = threadIdx.x;
  const int lane = t & 63, w = t >> 6;       // 8 waves
  const int wr = w >> 2, wc = w & 3;         // 2 (M) x 4 (N)
  const int lr = lane & 15, lg = lane >> 4;
  const int nwg = gridDim.x;
  const int swz = (blockIdx.x & 7) * (nwg >> 3) + (blockIdx.x >> 3);
  const int m0 = (swz / NBN) * QM;
  const int n0g = (swz % NBN) * QN;
  const int NT = K / QKS;                    // 64

  f32x4 acc[8][4] = {};                      // 128 VGPR

  auto stageA = [&](int kt, int b) {
    unsigned short* dst = &lds[b * QLDSB];
    const size_t k0 = (size_t)kt * QKS;
    #pragma unroll
    for (int c = 0; c < 2; c++) {
      int ci = c * 512 + t;
      int row = ci >> 2, slot = ci & 3;
      GLOAD16(A + (size_t)(m0 + row) * K + k0 + slot * 8,
              dst + (size_t)(c * 512 + w * 64) * 8);
    }
  };
  auto stageB = [&](int kt, int b) {
    unsigned short* dst = &lds[b * QLDSB + QM * QKS];
    const size_t k0 = (size_t)kt * QKS;
    #pragma unroll
    for (int c = 0; c < 2; c++) {
      int ci = c * 512 + t;
      int row = ci >> 2, slot = ci & 3;
      GLOAD16(Bt + (size_t)(n0g + row) * K + k0 + slot * 8,
              dst + (size_t)(c * 512 + w * 64) * 8);
    }
  };

  const unsigned short* buf = nullptr;
  auto ldA = [&](int mi) -> bf16x8 {
    int r = wr * 128 + mi * 16 + lr;
    return *(const bf16x8*)((const char*)buf + r * 64 + lg * 16);
  };
  auto ldB = [&](int ni) -> bf16x8 {
    int r = wc * 64 + ni * 16 + lr;
    return *(const bf16x8*)((const char*)(buf + QM * QKS) + r * 64 + lg * 16);
  };

  stageA(0, 0); stageB(0, 0);
  stageA(1, 1); stageB(1, 1);

  for (int kt = 0; kt < NT; kt++) {
    if (kt + 1 < NT) { asm volatile("s_waitcnt vmcnt(4)" ::: "memory"); }
    else             { asm volatile("s_waitcnt vmcnt(0)" ::: "memory"); }
    __builtin_amdgcn_s_barrier();
    buf = &lds[(kt & 3) * QLDSB];
    const int kt2 = kt + 2, b2 = kt2 & 3;

    bf16x8 bfr[4], afr[4];
    #pragma unroll
    for (int ni = 0; ni < 4; ni++) bfr[ni] = ldB(ni);
    #pragma unroll
    for (int mi = 0; mi < 4; mi++) afr[mi] = ldA(mi);
    if (kt2 < NT) stageA(kt2, b2);
    asm volatile("s_waitcnt lgkmcnt(0)" ::: "memory");
    __builtin_amdgcn_sched_barrier(0);
    __builtin_amdgcn_s_setprio(1);
    #pragma unroll
    for (int mi = 0; mi < 4; mi++)
      #pragma unroll
      for (int ni = 0; ni < 4; ni++)
        acc[mi][ni] = __builtin_amdgcn_mfma_f32_16x16x32_bf16(afr[mi], bfr[ni], acc[mi][ni], 0, 0, 0);
    __builtin_amdgcn_s_setprio(0);
    __builtin_amdgcn_s_barrier();

    bf16x8 afr2[4];
    #pragma unroll
    for (int mi = 0; mi < 4; mi++) afr2[mi] = ldA(mi + 4);
    if (kt2 < NT) stageB(kt2, b2);
    asm volatile("s_waitcnt lgkmcnt(0)" ::: "memory");
    __builtin_amdgcn_sched_barrier(0);
    __builtin_amdgcn_s_setprio(1);
    #pragma unroll
    for (int mi = 0; mi < 4; mi++)
      #pragma unroll
      for (int ni = 0; ni < 4; ni++)
        acc[mi + 4][ni] = __builtin_amdgcn_mfma_f32_16x16x32_bf16(afr2[mi], bfr[ni], acc[mi + 4][ni], 0, 0, 0);
    __builtin_amdgcn_s_setprio(0);
  }

  // RoPE epilogue: sel 0=Q (scaled), 1=K; head-major [bh][t][d].
  const int selK = n0g >> 11;
  unsigned short* dst = selK ? KrO : QrO;
  const float qm = selK ? 1.0f : QSCALE;
  #pragma unroll
  for (int mi = 0; mi < 8; mi++)
    #pragma unroll
    for (int j = 0; j < 4; j++) {
      int row = m0 + wr * 128 + mi * 16 + lg * 4 + j;
      int bb = row >> 11, tt = row & (TSEQ - 1);
      #pragma unroll
      for (int ni = 0; ni < 4; ni++) {
        int c2 = (n0g + wc * 64 + ni * 16 + lr) & 2047;
        int d = c2 & 127, hh = c2 >> 7;
        float v = acc[mi][ni][j];
        float px = __shfl_xor(v, 1);   // rotary partner: col d^1 = lane lr^1
        float cc = ct[tt * 64 + (d >> 1)], ss = st[tt * 64 + (d >> 1)];
        float o = (d & 1) ? (px * ss + v * cc) : (v * cc - px * ss);
        dst[(((size_t)(bb * NH + hh)) * TSEQ + tt) * DHD + d] = f2bf(o * qm);
      }
    }
}

// ---------------- gemm256: 256x128/BK=64 (R10-proven) ----------------
// MODE 0: C = A@Bt^T, f32 [M][N] (proj). MODE 2: V-GEMM + fused V-transpose
#define G2M 256
#define G2N 128
#define G2K 64
template<int MODE>
__global__ __launch_bounds__(512, 2) void gemm256(
    const unsigned short* __restrict__ A,
    const unsigned short* __restrict__ Bt,
    void* __restrict__ Cp, int K, int N, int NBN) {
  __shared__ unsigned short lds[3 * (G2M + G2N) * G2K];  // 147456 B
  const int t = threadIdx.x;
  const int lane = t & 63, w = t >> 6;
  const int wr = w >> 2, wc = w & 3;
  const int lr = lane & 15, lg = lane >> 4;
  const int nwg = gridDim.x;
  const int swz = (blockIdx.x & 7) * (nwg >> 3) + (blockIdx.x >> 3);
  const int m0 = (swz / NBN) * G2M;
  const int n0g = (swz % NBN) * G2N;
  const int NT = K / G2K;

  f32x4 acc[8][2] = {};

  auto stageA = [&](int kt, int b) {
    unsigned short* dst = &lds[b * (G2M + G2N) * G2K];
    const size_t k0 = (size_t)kt * G2K;
    #pragma unroll
    for (int c = 0; c < 4; c++) {
      int i = c * 512 + t;
      int row = i >> 3, slot = i & 7;
      int sslot = slot ^ (row & 7);
      GLOAD16(A + (size_t)(m0 + row) * K + k0 + sslot * 8,
              dst + (size_t)(c * 512 + w * 64) * 8);
    }
  };
  auto stageB = [&](int kt, int b) {
    unsigned short* dst = &lds[b * (G2M + G2N) * G2K + G2M * G2K];
    const size_t k0 = (size_t)kt * G2K;
    #pragma unroll
    for (int c = 0; c < 2; c++) {
      int i = c * 512 + t;
      int row = i >> 3, slot = i & 7;
      int sslot = slot ^ (row & 7);
      GLOAD16(Bt + (size_t)(n0g + row) * K + k0 + sslot * 8,
              dst + (size_t)(c * 512 + w * 64) * 8);
    }
  };

  const unsigned short* bufA = nullptr;
  const unsigned short* bufB = nullptr;
  auto ldA = [&](int mi, int ks) -> bf16x8 {
    int r = wr * 128 + mi * 16 + lr;
    int cb = (ks * 64 + lg * 16) ^ ((r & 7) << 4);
    return *(const bf16x8*)((const char*)bufA + r * 128 + cb);
  };
  auto ldB = [&](int ni, int ks) -> bf16x8 {
    int r = wc * 32 + ni * 16 + lr;
    int cb = (ks * 64 + lg * 16) ^ ((r & 7) << 4);
    return *(const bf16x8*)((const char*)bufB + r * 128 + cb);
  };

  stageA(0, 0); stageB(0, 0);
  stageA(1, 1); stageB(1, 1);

  for (int kt = 0; kt < NT; kt++) {
    if (kt + 1 < NT) { asm volatile("s_waitcnt vmcnt(6)" ::: "memory"); }
    else             { asm volatile("s_waitcnt vmcnt(0)" ::: "memory"); }
    __builtin_amdgcn_s_barrier();
    const int b = kt % 3;
    bufA = &lds[b * (G2M + G2N) * G2K];
    bufB = bufA + G2M * G2K;
    const int kt2 = kt + 2, b2 = kt2 % 3;

    bf16x8 bfr[2][2], afr[4][2];
    #pragma unroll
    for (int ni = 0; ni < 2; ni++)
      #pragma unroll
      for (int ks = 0; ks < 2; ks++) bfr[ni][ks] = ldB(ni, ks);
    #pragma unroll
    for (int mi = 0; mi < 4; mi++)
      #pragma unroll
      for (int ks = 0; ks < 2; ks++) afr[mi][ks] = ldA(mi, ks);
    if (kt2 < NT) stageA(kt2, b2);
    asm volatile("s_waitcnt lgkmcnt(0)" ::: "memory");
    __builtin_amdgcn_sched_barrier(0);
    __builtin_amdgcn_s_setprio(1);
    #pragma unroll
    for (int mi = 0; mi < 4; mi++)
      #pragma unroll
      for (int ni = 0; ni < 2; ni++)
        #pragma unroll
        for (int ks = 0; ks < 2; ks++)
          acc[mi][ni] = __builtin_amdgcn_mfma_f32_16x16x32_bf16(afr[mi][ks], bfr[ni][ks], acc[mi][ni], 0, 0, 0);
    __builtin_amdgcn_s_setprio(0);
    __builtin_amdgcn_s_barrier();

    bf16x8 afr2[4][2];
    #pragma unroll
    for (int mi = 0; mi < 4; mi++)
      #pragma unroll
      for (int ks = 0; ks < 2; ks++) afr2[mi][ks] = ldA(mi + 4, ks);
    if (kt2 < NT) stageB(kt2, b2);
    asm volatile("s_waitcnt lgkmcnt(0)" ::: "memory");
    __builtin_amdgcn_sched_barrier(0);
    __builtin_amdgcn_s_setprio(1);
    #pragma unroll
    for (int mi = 0; mi < 4; mi++)
      #pragma unroll
      for (int ni = 0; ni < 2; ni++)
        #pragma unroll
        for (int ks = 0; ks < 2; ks++)
          acc[mi + 4][ni] = __builtin_amdgcn_mfma_f32_16x16x32_bf16(afr2[mi][ks], bfr[ni][ks], acc[mi + 4][ni], 0, 0, 0);
    __builtin_amdgcn_s_setprio(0);
  }

  if (MODE == 0) {
    #pragma unroll
    for (int mi = 0; mi < 8; mi++)
      #pragma unroll
      for (int j = 0; j < 4; j++) {
        int row = m0 + wr * 128 + mi * 16 + lg * 4 + j;
        #pragma unroll
        for (int ni = 0; ni < 2; ni++) {
          int cg = n0g + wc * 32 + ni * 16 + lr;
          ((float*)Cp)[(size_t)row * N + cg] = acc[mi][ni][j];
        }
      }
  } else {
    // fused V-transpose: one head panel (128 d x 256 t) per block
    __builtin_amdgcn_s_barrier();     // drain all waves' K-loop LDS reads
    unsigned short* Lt = lds;         // [128 d][264] shorts (528B rows)
    #pragma unroll
    for (int mi = 0; mi < 8; mi++)
      #pragma unroll
      for (int j = 0; j < 4; j++) {
        int tl = wr * 128 + mi * 16 + lg * 4 + j;
        #pragma unroll
        for (int ni = 0; ni < 2; ni++) {
          int d = wc * 32 + ni * 16 + lr;
          Lt[d * 264 + tl] = f2bf(acc[mi][ni][j]);
        }
      }
    __builtin_amdgcn_s_barrier();
    const int hh = n0g >> 7;
    const int bb = m0 >> 11, t0 = m0 & (TSEQ - 1);
    const int bh = bb * NH + hh;
    unsigned short* VtO = (unsigned short*)Cp;
    #pragma unroll
    for (int c = 0; c < 8; c++) {
      int ci = c * 512 + t;
      int d = ci >> 5, tc = ci & 31;
      bf16x8 v = *(const bf16x8*)&Lt[d * 264 + tc * 8];
      *(bf16x8*)&VtO[((size_t)bh * DHD + d) * TSEQ + t0 + tc * 8] = v;
    }
  }
}

// ---------------- causal flash attention, 8-wave paired q-tiles ----------------
// R15 counter evidence: 83 µs, FETCH 152 MB (~3.5x ideal), MfmaUtil 17.6% —
// HBM/L2-locality-bound, not compute. Fix (T1): 1D grid with bh FASTEST
// (bid & 31) so all 16 blocks of a head get linear IDs ≡ bh (mod 8) -> same
// XCD under round-robin dispatch. Each XCD L2 (4 MB) then holds its 4 heads'
// K+V (4 MB) and cross-block re-reads become L2 hits.
__global__ __launch_bounds__(512, 4) void attn_kernel(
    const unsigned short* __restrict__ Qr,
    const unsigned short* __restrict__ Kr,
    const unsigned short* __restrict__ VTt,
    unsigned short* __restrict__ Oa) {
  __shared__ unsigned short Ks[64 * 128];
  __shared__ unsigned short Vs[128 * 64];
  __shared__ unsigned short Ps[8 * 16 * 64];
  const int t = threadIdx.x;
  const int lane = t & 63, w = t >> 6;     // 8 waves
  const int wv = w & 3, half = w >> 2;     // half 0 = tile B, 1 = tile A
  const int lr = lane & 15, lg = lane >> 4;
  const int bid = blockIdx.x;
  const int p = bid >> 5;                  // 0..15
  const int bh = bid & 31;                 // head fastest -> same XCD per head
  const int qA = p, qB = 31 - p;           // qB > qA always
  const int myq = half ? qA : qB;
  const int q0 = myq * 64;
  const int nt = myq + 1;                  // my tile count
  const int ntB = qB + 1;                  // staging trip count
  const unsigned short* Qh = Qr + (size_t)bh * TSEQ * DHD;
  const unsigned short* Kh = Kr + (size_t)bh * TSEQ * DHD;
  const unsigned short* Vh = VTt + (size_t)bh * DHD * TSEQ;

  bf16x8 qf[4];
  #pragma unroll
  for (int ks = 0; ks < 4; ks++)
    qf[ks] = *(const bf16x8*)&Qh[((size_t)(q0 + wv * 16 + lr)) * DHD + ks * 32 + lg * 8];

  f32x4 oacc[8] = {};
  float ps[4] = {};
  unsigned short* Pw = &Ps[w * 16 * 64];

  for (int jt = 0; jt < ntB; jt++) {
    const int j0 = jt * 64;
    #pragma unroll
    for (int c = 0; c < 2; c++) {
      int ci = c * 512 + t;
      int row = ci >> 4, slot = ci & 15;
      GLOAD16(Kh + (size_t)(j0 + row) * DHD + (slot ^ (row & 7)) * 8,
              &Ks[(c * 512 + w * 64) * 8]);
    }
    #pragma unroll
    for (int c = 0; c < 2; c++) {
      int ci = c * 512 + t;
      int row = ci >> 3, slot = ci & 7;
      GLOAD16(Vh + (size_t)row * TSEQ + j0 + (slot ^ (row & 7)) * 8,
              &Vs[(c * 512 + w * 64) * 8]);
    }
    __syncthreads();
    if (jt < nt) {
      const bool diag = (jt == nt - 1);
      f32x4 sv[4] = {};
      #pragma unroll
      for (int n = 0; n < 4; n++) {
        #pragma unroll
        for (int ks = 0; ks < 4; ks++) {
          int row = n * 16 + lr;
          int byteoff = row * 256 + (((ks * 64 + lg * 16)) ^ ((row & 7) << 4));
          bf16x8 kf = *(const bf16x8*)((const char*)Ks + byteoff);
          sv[n] = __builtin_amdgcn_mfma_f32_16x16x32_bf16(qf[ks], kf, sv[n], 0, 0, 0);
        }
      }
      if (diag) {
        #pragma unroll
        for (int n = 0; n < 4; n++) {
          int kcol = j0 + n * 16 + lr;
          #pragma unroll
          for (int j = 0; j < 4; j++)
            if (kcol > q0 + wv * 16 + lg * 4 + j) sv[n][j] = -INFINITY;
        }
      }
      #pragma unroll
      for (int n = 0; n < 4; n++) {
        #pragma unroll
        for (int j = 0; j < 4; j++) {
          float pv = exp2f(sv[n][j]);
          ps[j] += pv;
          int prow = lg * 4 + j;
          int pcol = n * 16 + lr;
          int byteoff = (prow * 128 + pcol * 2) ^ ((prow & 7) << 4);
          *(unsigned short*)((char*)Pw + byteoff) = f2bf(pv);
        }
      }
      bf16x8 pa[2];
      #pragma unroll
      for (int kk = 0; kk < 2; kk++) {
        int byteoff = lr * 128 + (((kk * 64 + lg * 16)) ^ ((lr & 7) << 4));
        pa[kk] = *(const bf16x8*)((const char*)Pw + byteoff);
      }
      #pragma unroll
      for (int n2 = 0; n2 < 8; n2++) {
        #pragma unroll
        for (int kk = 0; kk < 2; kk++) {
          int row = n2 * 16 + lr;
          int byteoff = row * 128 + (((kk * 64 + lg * 16)) ^ ((row & 7) << 4));
          bf16x8 vf = *(const bf16x8*)((const char*)Vs + byteoff);
          oacc[n2] = __builtin_amdgcn_mfma_f32_16x16x32_bf16(pa[kk], vf, oacc[n2], 0, 0, 0);
        }
      }
    }
    __syncthreads();
  }

  #pragma unroll
  for (int m = 1; m < 16; m <<= 1)
    #pragma unroll
    for (int j = 0; j < 4; j++) ps[j] += __shfl_xor(ps[j], m);
  const int h = bh & (NH - 1), b = bh >> 4;
  #pragma unroll
  for (int j = 0; j < 4; j++) {
    float inv = 1.0f / ps[j];
    int tt = q0 + wv * 16 + lg * 4 + j;
    size_t base = ((size_t)(b * TSEQ + tt)) * DM + h * DHD;
    #pragma unroll
    for (int n2 = 0; n2 < 8; n2++)
      Oa[base + n2 * 16 + lr] = f2bf(oacc[n2][j] * inv);
  }
}

// ---------------- launch ----------------
extern "C" void kernel_launch(void* const* d_in, const int* in_sizes, int n_in,
                              void* d_out, int out_size, void* d_ws, size_t ws_size,
                              hipStream_t stream) {
  const float* x  = (const float*)d_in[0];
  const int*   pos = (const int*)d_in[1];
  const float* Wq = (const float*)d_in[2];
  const float* Wk = (const float*)d_in[3];
  const float* Wv = (const float*)d_in[4];
  const float* Wp = (const float*)d_in[5];
  float* out = (float*)d_out;

  char* wsp = (char*)d_ws;
  auto alloc = [&](size_t bytes) { char* p = wsp; wsp += (bytes + 255) & ~(size_t)255; return p; };
  unsigned short* xb  = (unsigned short*)alloc((size_t)NTOK * DM * 2);  // x; later Oa
  unsigned short* wqb = (unsigned short*)alloc((size_t)DM * DM * 2);    // wq/wk/wv/wp contiguous
  unsigned short* wkb = (unsigned short*)alloc((size_t)DM * DM * 2);
  unsigned short* wvb = (unsigned short*)alloc((size_t)DM * DM * 2);
  unsigned short* wpb = (unsigned short*)alloc((size_t)DM * DM * 2);
  unsigned short* Qb  = (unsigned short*)alloc((size_t)NTOK * DM * 2);  // roped Q, head-major
  unsigned short* Kb  = (unsigned short*)alloc((size_t)NTOK * DM * 2);  // roped K, head-major
  unsigned short* VTt = (unsigned short*)alloc((size_t)NTOK * DM * 2);  // V^T head-major (direct)
  float* ctab = (float*)alloc((size_t)TSEQ * 64 * 4);
  float* stab = (float*)alloc((size_t)TSEQ * 64 * 4);
  unsigned short* Oa = xb;   // x dead after QKV projection
  (void)wkb;

  int n4x = NTOK * DM / 4, n4w = DM * DM / 4;
  cvt_kernel<<<2048, 256, 0, stream>>>(x, xb, n4x);
  cvt4_kernel<<<dim3(256, 4), 256, 0, stream>>>(Wq, Wk, Wv, Wp, wqb, n4w);
  rope_table_kernel<<<(TSEQ * 64) / 256, 256, 0, stream>>>(pos, ctab, stab);

  // QK projection + RoPE epilogue: Bt = [Wq;Wk] (N=4096), grid 16x16 = 256 (1 round)
  gemmsq<<<(NTOK / QM) * (2 * DM / QN), 512, 0, stream>>>(
      xb, wqb, Qb, Kb, ctab, stab, DM, 2 * DM / QN);

  // V projection + fused V-transpose: grid 16x16 = 256 (1 round)
  gemm256<2><<<(NTOK / G2M) * (DM / G2N), 512, 0, stream>>>(
      xb, wvb, VTt, DM, DM, DM / G2N);

  // attention: 1D grid, bh-fastest for XCD L2 locality (all blocks of a head
  // land on XCD bh%8; 4 heads/XCD = 4 MB K+V = L2 capacity)
  attn_kernel<<<512, 512, 0, stream>>>(Qb, Kb, VTt, Oa);

  // output projection: 256-block gemm256, 1 block/CU = all CUs busy
  gemm256<0><<<(NTOK / G2M) * (DM / G2N), 512, 0, stream>>>(
      Oa, wpb, out, DM, DM, DM / G2N);
}